// Round 1
// baseline (56695.148 us; speedup 1.0000x reference)
//
#include <hip/hip_runtime.h>
#include <math.h>

// ---- problem constants ----
constexpr int SEQ_T  = 2048;
constexpr int BATCH  = 128;
constexpr int KDIM   = 128;
constexpr int VDIM   = 128;
constexpr int EDIM   = 400;
constexpr int HDIM   = 300;
constexpr int GDIM   = 1200;    // 4*H
constexpr int NVOCAB = 33;
constexpr int MAXLEN = 500;
constexpr int SOS_TOK = 5;
constexpr int NCHUNK = 16;      // t-chunks per b
constexpr int CHT    = 128;     // t per chunk
constexpr int PROW   = 136;     // floats per partial row: accV[128], M, S, pad
constexpr long long NLOGITS = (long long)MAXLEN * BATCH * NVOCAB; // 2,112,000

// ---- ws float-element offsets ----
constexpr size_t OFF_H     = 0;        // 128*300
constexpr size_t OFF_C0    = 38400;    // 128*300 (ping)
constexpr size_t OFF_C1    = 76800;    // 128*300 (pong)
constexpr size_t OFF_GATES = 115200;   // 128*1200
constexpr size_t OFF_QUERY = 268800;   // 128*128
constexpr size_t OFF_CTX   = 285184;   // 128*128
constexpr size_t OFF_WPHIT = 301568;   // 300*128
constexpr size_t OFF_PART  = 339968;   // 2048*136
constexpr size_t OFF_CHARS = 618496;   // 128 int
// reordered [B][T][K] copies of keys/values (primary path)
constexpr size_t NKV       = (size_t)SEQ_T * BATCH * KDIM;   // 33,554,432 floats
constexpr size_t OFF_KEYSR = 655360;
constexpr size_t OFF_VALSR = OFF_KEYSR + NKV;
constexpr size_t WS_NEED_F = OFF_VALSR + NKV;                // ~271 MB

// ---------------------------------------------------------------------------
// one-time: W_phi [128][300] -> W_phiT [300][128]
__global__ __launch_bounds__(256) void k_transpose(
    const float* __restrict__ W_phi, float* __restrict__ wphiT) {
  int i = blockIdx.x * 256 + threadIdx.x;
  if (i < HDIM * KDIM) {
    int j = i >> 7, kq = i & 127;
    wphiT[i] = W_phi[kq * HDIM + j];
  }
}

// one-time: h,c,chars init + initial query
__global__ __launch_bounds__(128) void k_init(
    const float* __restrict__ h0, const float* __restrict__ c0,
    const float* __restrict__ b_phi, const float* __restrict__ wphiT,
    float* __restrict__ h, float* __restrict__ c,
    float* __restrict__ query, int* __restrict__ chars_) {
  const int b = blockIdx.x;
  const int tid = threadIdx.x;
  for (int j = tid; j < HDIM; j += 128) {
    h[b * HDIM + j] = h0[j];
    c[b * HDIM + j] = c0[j];
  }
  {
    float q = b_phi[tid];
    for (int j = 0; j < HDIM; ++j) q += h0[j] * wphiT[j * KDIM + tid];
    query[b * KDIM + tid] = q;
  }
  if (tid == 0) chars_[b] = SOS_TOK;
}

// ---------------------------------------------------------------------------
// one-time: [T][B][128] -> [B][T][128] so each att block streams contiguously.
// grid (128 b, 128 t-tiles of 16), 256 threads. Reads coalesced 512B rows,
// writes a contiguous 8KB region per block.
__global__ __launch_bounds__(256) void k_reorder(
    const float* __restrict__ src, float* __restrict__ dst) {
  const int b  = blockIdx.x;
  const int tt = blockIdx.y * 16;
  const int tid = threadIdx.x;
  for (int i = tid; i < 512; i += 256) {      // 16 t * 32 float4
    const int tl = i >> 5, k4 = i & 31;
    const size_t t = (size_t)(tt + tl);
    const float4 v = *(const float4*)(src + (t * BATCH + b) * KDIM + k4 * 4);
    *(float4*)(dst + ((size_t)b * SEQ_T + t) * KDIM + k4 * 4) = v;
  }
}

// ---------------------------------------------------------------------------
// k_cell: LSTM cell -> h,c ; logits/argmax -> out/chars ; query -> query_g.
// grid 128 (one per b), 256 threads. Extracted from the streaming kernel so
// k_att has zero preamble and uniform blocks.
__global__ __launch_bounds__(256) void k_cell(
    const float* __restrict__ gates, const float* __restrict__ ctx_g,
    const float* __restrict__ W_proj, const float* __restrict__ b_proj,
    const float* __restrict__ b_phi, const float* __restrict__ wphiT,
    const float* __restrict__ c_in, float* __restrict__ c_out,
    float* __restrict__ h, float* __restrict__ query_g,
    int* __restrict__ chars_, float* __restrict__ out, int step) {
  const int b = blockIdx.x, tid = threadIdx.x;
  __shared__ float hs_cat[HDIM + VDIM];
  __shared__ float logit_s[NVOCAB];
  for (int j = tid; j < HDIM; j += 256) {
    const float gi = gates[b * GDIM + j];
    const float gf = gates[b * GDIM + HDIM + j];
    const float gg = gates[b * GDIM + 2 * HDIM + j];
    const float go = gates[b * GDIM + 3 * HDIM + j];
    const float cc = c_in[b * HDIM + j];
    const float si = 1.f / (1.f + expf(-gi));
    const float sf = 1.f / (1.f + expf(-gf));
    const float so = 1.f / (1.f + expf(-go));
    const float cn = sf * cc + si * tanhf(gg);
    const float hn = so * tanhf(cn);
    hs_cat[j] = hn;
    c_out[b * HDIM + j] = cn;
    h[b * HDIM + j] = hn;
  }
  if (tid < VDIM) hs_cat[HDIM + tid] = ctx_g[b * VDIM + tid];
  __syncthreads();
  // logits + argmax + emit
  const int w = tid >> 6, l = tid & 63;
  for (int j = w; j < NVOCAB; j += 4) {
    float p = 0.f;
    for (int e = l; e < HDIM + VDIM; e += 64) p += hs_cat[e] * W_proj[j * 428 + e];
    p += __shfl_xor(p, 1); p += __shfl_xor(p, 2); p += __shfl_xor(p, 4);
    p += __shfl_xor(p, 8); p += __shfl_xor(p, 16); p += __shfl_xor(p, 32);
    if (l == 0) logit_s[j] = p + b_proj[j];
  }
  __syncthreads();
  if (tid < NVOCAB) out[((size_t)step * BATCH + b) * NVOCAB + tid] = logit_s[tid];
  if (tid == 0) {
    float best = logit_s[0];
    int bi = 0;
    for (int j = 1; j < NVOCAB; ++j)
      if (logit_s[j] > best) { best = logit_s[j]; bi = j; }  // np first-max
    chars_[b] = bi;
    out[NLOGITS + (size_t)step * BATCH + b] = (float)bi;
  }
  // query from h_new (dual accumulator halves the dependent-FMA chain)
  if (tid < KDIM) {
    float q0 = b_phi[tid], q1 = 0.f;
    for (int j = 0; j < HDIM; j += 2) {
      q0 += hs_cat[j]     * wphiT[j * KDIM + tid];
      q1 += hs_cat[j + 1] * wphiT[(j + 1) * KDIM + tid];
    }
    query_g[b * KDIM + tid] = q0 + q1;
  }
}

// ---------------------------------------------------------------------------
// k_att_s: pure streaming attention over reordered [B][T][K] keys/values.
// grid (128 b, 16 chunks), 256 threads = 8 half-waves, each owning 16 t.
// Fused single pass: per t, energy (32-lane dot+reduce) then online-softmax
// value accumulation. Each half-wave streams two contiguous 8KB regions.
__global__ __launch_bounds__(256) void k_att_s(
    const float* __restrict__ keysR, const float* __restrict__ valsR,
    const float* __restrict__ query_g, float* __restrict__ partials) {
  const int b = blockIdx.x, chunk = blockIdx.y, tid = threadIdx.x;
  const int l32 = tid & 31;
  const int hw  = tid >> 5;                  // half-wave 0..7
  __shared__ __align__(16) float accs[8][128];
  __shared__ float stats[8][2];              // m, s per half-wave

  const float4 q4 = *(const float4*)(query_g + (size_t)b * KDIM + l32 * 4);
  const size_t t0 = (size_t)b * SEQ_T + chunk * CHT + hw * 16;
  const float* kp = keysR + t0 * KDIM + l32 * 4;
  const float* vp = valsR + t0 * VDIM + l32 * 4;

  float m = -1e30f, s = 0.f;
  float4 acc = make_float4(0.f, 0.f, 0.f, 0.f);
  for (int i = 0; i < 16; ++i) {
    const float4 kv = *(const float4*)(kp + (size_t)i * KDIM);
    const float4 vv = *(const float4*)(vp + (size_t)i * VDIM);
    float p = q4.x * kv.x + q4.y * kv.y + q4.z * kv.z + q4.w * kv.w;
    p += __shfl_xor(p, 1); p += __shfl_xor(p, 2); p += __shfl_xor(p, 4);
    p += __shfl_xor(p, 8); p += __shfl_xor(p, 16);   // all 32 lanes hold e_t
    const float mn = fmaxf(m, p);
    const float sc = expf(m - mn);           // first iter: expf(-huge)=0
    const float a  = expf(p - mn);
    s = s * sc + a;
    acc.x = acc.x * sc + a * vv.x;
    acc.y = acc.y * sc + a * vv.y;
    acc.z = acc.z * sc + a * vv.z;
    acc.w = acc.w * sc + a * vv.w;
    m = mn;
  }
  *(float4*)(&accs[hw][l32 * 4]) = acc;
  if (l32 == 0) { stats[hw][0] = m; stats[hw][1] = s; }
  __syncthreads();
  if (tid < 32) {                            // fixed-order deterministic combine
    float M = stats[0][0];
    for (int h2 = 1; h2 < 8; ++h2) M = fmaxf(M, stats[h2][0]);
    float S = 0.f;
    float4 o = make_float4(0.f, 0.f, 0.f, 0.f);
    for (int h2 = 0; h2 < 8; ++h2) {
      const float wgt = expf(stats[h2][0] - M);
      S += wgt * stats[h2][1];
      const float4 a4 = *(const float4*)(&accs[h2][tid * 4]);
      o.x += wgt * a4.x; o.y += wgt * a4.y; o.z += wgt * a4.z; o.w += wgt * a4.w;
    }
    const size_t r = (size_t)b * NCHUNK + chunk;
    *(float4*)(partials + r * PROW + tid * 4) = o;
    if (tid == 0) {
      partials[r * PROW + 128] = M;
      partials[r * PROW + 129] = S;
    }
  }
}

// ---------------------------------------------------------------------------
// k_gates: [combine partials -> ctx] + gates GEMM (proven, unchanged).
__global__ __launch_bounds__(256) void k_gates(
    const float* __restrict__ emb, const int* __restrict__ chars_,
    const float* __restrict__ partials, const float* __restrict__ h,
    const float* __restrict__ W_ih, const float* __restrict__ b_ih,
    const float* __restrict__ W_hh, const float* __restrict__ b_hh,
    float* __restrict__ gates, float* __restrict__ ctx_g) {
  const int bT = blockIdx.x * 16;
  const int jT = blockIdx.y * 32;
  const int tid = threadIdx.x;
  __shared__ float Xs[16 * 836];
  __shared__ float ctxs[16 * 128];
  {
    const int bl = tid >> 4, l16 = tid & 15;
    const int bg = bT + bl;
    const float* pb = partials + (size_t)bg * NCHUNK * PROW;
    float M = -INFINITY;
    for (int ci = 0; ci < NCHUNK; ++ci) M = fmaxf(M, pb[ci * PROW + 128]);
    float den = 0.f;
    float4 n0 = make_float4(0.f, 0.f, 0.f, 0.f);
    float4 n1 = make_float4(0.f, 0.f, 0.f, 0.f);
    for (int ci = 0; ci < NCHUNK; ++ci) {
      const float w = expf(pb[ci * PROW + 128] - M);
      den += w * pb[ci * PROW + 129];
      const float4 a0 = *(const float4*)(pb + ci * PROW + l16 * 8);
      const float4 a1 = *(const float4*)(pb + ci * PROW + l16 * 8 + 4);
      n0.x += w * a0.x; n0.y += w * a0.y; n0.z += w * a0.z; n0.w += w * a0.w;
      n1.x += w * a1.x; n1.y += w * a1.y; n1.z += w * a1.z; n1.w += w * a1.w;
    }
    const float inv = 1.f / den;
    n0.x *= inv; n0.y *= inv; n0.z *= inv; n0.w *= inv;
    n1.x *= inv; n1.y *= inv; n1.z *= inv; n1.w *= inv;
    *(float4*)(ctxs + bl * 128 + l16 * 8)     = n0;
    *(float4*)(ctxs + bl * 128 + l16 * 8 + 4) = n1;
    if (blockIdx.y == 0) {
      *(float4*)(ctx_g + bg * 128 + l16 * 8)     = n0;
      *(float4*)(ctx_g + bg * 128 + l16 * 8 + 4) = n1;
    }
  }
  __syncthreads();
  for (int bb = 0; bb < 16; ++bb) {
    const int bg = bT + bb;
    const int ch = chars_[bg];
    for (int k = tid; k < 832; k += 256) {
      float x;
      if (k < EDIM)      x = emb[ch * EDIM + k];
      else if (k < 528)  x = ctxs[bb * 128 + (k - EDIM)];
      else if (k < 828)  x = h[bg * HDIM + (k - 528)];
      else               x = 0.f;
      Xs[bb * 836 + k] = x;
    }
  }
  __syncthreads();
  const int bLoc = tid & 15;
  const int jLoc = tid >> 4;
  const int j0 = jT + jLoc * 2;
  if (j0 >= GDIM) return;
  const int j1 = j0 + 1;
  const int bg = bT + bLoc;
  float acc0 = 0.f, acc1 = 0.f;
  const float4* xr = (const float4*)(Xs + bLoc * 836);
  {
    const float4* w0 = (const float4*)(W_ih + (size_t)j0 * 528);
    const float4* w1 = (const float4*)(W_ih + (size_t)j1 * 528);
    for (int k4 = 0; k4 < 132; ++k4) {
      const float4 xv = xr[k4];
      const float4 a = w0[k4];
      const float4 bv = w1[k4];
      acc0 += xv.x * a.x + xv.y * a.y + xv.z * a.z + xv.w * a.w;
      acc1 += xv.x * bv.x + xv.y * bv.y + xv.z * bv.z + xv.w * bv.w;
    }
  }
  {
    const float4* xh = (const float4*)(Xs + bLoc * 836 + 528);
    const float4* g0 = (const float4*)(W_hh + (size_t)j0 * HDIM);
    const float4* g1 = (const float4*)(W_hh + (size_t)j1 * HDIM);
    for (int k4 = 0; k4 < 75; ++k4) {
      const float4 xv = xh[k4];
      const float4 a = g0[k4];
      const float4 bv = g1[k4];
      acc0 += xv.x * a.x + xv.y * a.y + xv.z * a.z + xv.w * a.w;
      acc1 += xv.x * bv.x + xv.y * bv.y + xv.z * bv.z + xv.w * bv.w;
    }
  }
  gates[bg * GDIM + j0] = acc0 + b_ih[j0] + b_hh[j0];
  gates[bg * GDIM + j1] = acc1 + b_ih[j1] + b_hh[j1];
}

// ---------------------------------------------------------------------------
// Legacy fused k_att (fallback when workspace can't hold reordered copies).
__global__ __launch_bounds__(256) void k_att_fb(
    const float* __restrict__ keys, const float* __restrict__ values,
    const float* __restrict__ gates, const float* __restrict__ ctx_g,
    const float* __restrict__ W_proj, const float* __restrict__ b_proj,
    const float* __restrict__ b_phi, const float* __restrict__ wphiT,
    const float* __restrict__ c_in, float* __restrict__ c_out,
    float* __restrict__ h, const float* __restrict__ query_g,
    int* __restrict__ chars_, float* __restrict__ partials,
    float* __restrict__ out, int step) {
  const int b = blockIdx.x, chunk = blockIdx.y, tid = threadIdx.x;
  __shared__ float hs_cat[HDIM + VDIM];
  __shared__ float logit_s[NVOCAB];
  __shared__ float qs[KDIM];
  __shared__ float e_s[CHT];
  __shared__ float att[CHT];
  __shared__ float red[8];
  __shared__ __align__(16) float redv[8 * 33 * 4];

  if (step >= 0) {
    for (int j = tid; j < HDIM; j += 256) {
      const float gi = gates[b * GDIM + j];
      const float gf = gates[b * GDIM + HDIM + j];
      const float gg = gates[b * GDIM + 2 * HDIM + j];
      const float go = gates[b * GDIM + 3 * HDIM + j];
      const float cc = c_in[b * HDIM + j];
      const float si = 1.f / (1.f + expf(-gi));
      const float sf = 1.f / (1.f + expf(-gf));
      const float so = 1.f / (1.f + expf(-go));
      const float cn = sf * cc + si * tanhf(gg);
      const float hn = so * tanhf(cn);
      hs_cat[j] = hn;
      if (chunk == 0) { c_out[b * HDIM + j] = cn; h[b * HDIM + j] = hn; }
    }
    if (chunk == 0 && tid < VDIM) hs_cat[HDIM + tid] = ctx_g[b * VDIM + tid];
    __syncthreads();
    if (chunk == 0) {
      const int w = tid >> 6, l = tid & 63;
      for (int j = w; j < NVOCAB; j += 4) {
        float p = 0.f;
        for (int e = l; e < HDIM + VDIM; e += 64) p += hs_cat[e] * W_proj[j * 428 + e];
        p += __shfl_xor(p, 1); p += __shfl_xor(p, 2); p += __shfl_xor(p, 4);
        p += __shfl_xor(p, 8); p += __shfl_xor(p, 16); p += __shfl_xor(p, 32);
        if (l == 0) logit_s[j] = p + b_proj[j];
      }
      __syncthreads();
      if (tid < NVOCAB) out[((size_t)step * BATCH + b) * NVOCAB + tid] = logit_s[tid];
      if (tid == 0) {
        float best = logit_s[0];
        int bi = 0;
        for (int j = 1; j < NVOCAB; ++j)
          if (logit_s[j] > best) { best = logit_s[j]; bi = j; }
        chars_[b] = bi;
        out[NLOGITS + (size_t)step * BATCH + b] = (float)bi;
      }
    }
    if (tid < KDIM) {
      float q = b_phi[tid];
      for (int j = 0; j < HDIM; ++j) q += hs_cat[j] * wphiT[j * KDIM + tid];
      qs[tid] = q;
    }
  } else {
    if (tid < KDIM) qs[tid] = query_g[b * KDIM + tid];
  }
  __syncthreads();

  const int wave = tid >> 6, lane = tid & 63;
  const int half = lane >> 5, l32 = lane & 31;
  {
    const float4 q4 = *(const float4*)(qs + l32 * 4);
    const int tl0 = wave * 32;
    for (int i = 0; i < 16; ++i) {
      const int tl = tl0 + 2 * i + half;
      const int t = chunk * CHT + tl;
      const float4 kv = *(const float4*)(keys + ((size_t)t * BATCH + b) * KDIM + l32 * 4);
      float p = q4.x * kv.x + q4.y * kv.y + q4.z * kv.z + q4.w * kv.w;
      p += __shfl_xor(p, 1); p += __shfl_xor(p, 2); p += __shfl_xor(p, 4);
      p += __shfl_xor(p, 8); p += __shfl_xor(p, 16);
      if (l32 == 0) e_s[tl] = p;
    }
  }
  __syncthreads();

  float m = (tid < CHT) ? e_s[tid] : -INFINITY;
  for (int off = 32; off; off >>= 1) m = fmaxf(m, __shfl_xor(m, off));
  if ((tid & 63) == 0) red[tid >> 6] = m;
  __syncthreads();
  const float M = fmaxf(fmaxf(red[0], red[1]), fmaxf(red[2], red[3]));
  float ex = 0.f;
  if (tid < CHT) { ex = expf(e_s[tid] - M); att[tid] = ex; }
  for (int off = 32; off; off >>= 1) ex += __shfl_xor(ex, off);
  if ((tid & 63) == 0) red[4 + (tid >> 6)] = ex;
  __syncthreads();
  const float S = red[4] + red[5] + red[6] + red[7];

  const int v4 = tid & 31, tsub = tid >> 5;
  float4 acc = make_float4(0.f, 0.f, 0.f, 0.f);
  const float* vb = values + (size_t)b * VDIM + v4 * 4;
  for (int i = 0; i < 16; ++i) {
    const int tl = i * 8 + tsub;
    const float a = att[tl];
    const float4 val = *(const float4*)(vb + (size_t)(chunk * CHT + tl) * BATCH * VDIM);
    acc.x += a * val.x; acc.y += a * val.y; acc.z += a * val.z; acc.w += a * val.w;
  }
  *(float4*)(redv + (tsub * 33 + v4) * 4) = acc;
  __syncthreads();
  const size_t r = (size_t)b * NCHUNK + chunk;
  if (tid < 32) {
    float4 s4 = *(const float4*)(redv + tid * 4);
    for (int p = 1; p < 8; ++p) {
      const float4 rr = *(const float4*)(redv + (p * 33 + tid) * 4);
      s4.x += rr.x; s4.y += rr.y; s4.z += rr.z; s4.w += rr.w;
    }
    *(float4*)(partials + r * PROW + tid * 4) = s4;
  }
  if (tid == 0) {
    partials[r * PROW + 128] = M;
    partials[r * PROW + 129] = S;
  }
}

// ---------------------------------------------------------------------------
extern "C" void kernel_launch(void* const* d_in, const int* in_sizes, int n_in,
                              void* d_out, int out_size, void* d_ws, size_t ws_size,
                              hipStream_t stream) {
  (void)in_sizes; (void)n_in; (void)out_size;
  const float* keys   = (const float*)d_in[0];
  const float* values = (const float*)d_in[1];
  const float* emb    = (const float*)d_in[2];
  const float* W_phi  = (const float*)d_in[3];
  const float* b_phi  = (const float*)d_in[4];
  const float* W_ih   = (const float*)d_in[5];
  const float* b_ih   = (const float*)d_in[6];
  const float* W_hh   = (const float*)d_in[7];
  const float* b_hh   = (const float*)d_in[8];
  const float* W_proj = (const float*)d_in[9];
  const float* b_proj = (const float*)d_in[10];
  const float* h0     = (const float*)d_in[11];
  const float* c0     = (const float*)d_in[12];
  float* out = (float*)d_out;

  float* F = (float*)d_ws;
  float* f_h     = F + OFF_H;
  float* f_c[2]  = {F + OFF_C0, F + OFF_C1};
  float* f_gates = F + OFF_GATES;
  float* f_query = F + OFF_QUERY;
  float* f_ctx   = F + OFF_CTX;
  float* f_wphiT = F + OFF_WPHIT;
  float* f_part  = F + OFF_PART;
  int*   i_chars = (int*)(F + OFF_CHARS);

  k_transpose<<<150, 256, 0, stream>>>(W_phi, f_wphiT);
  k_init<<<BATCH, 128, 0, stream>>>(h0, c0, b_phi, f_wphiT, f_h, f_c[0],
                                    f_query, i_chars);

  const bool big = ws_size >= WS_NEED_F * sizeof(float);
  if (big) {
    float* kR = F + OFF_KEYSR;
    float* vR = F + OFF_VALSR;
    k_reorder<<<dim3(BATCH, SEQ_T / 16), 256, 0, stream>>>(keys, kR);
    k_reorder<<<dim3(BATCH, SEQ_T / 16), 256, 0, stream>>>(values, vR);
    // initial attend(h0): query from k_init
    k_att_s<<<dim3(BATCH, NCHUNK), 256, 0, stream>>>(kR, vR, f_query, f_part);
    for (int s = 0; s < MAXLEN; ++s) {
      k_gates<<<dim3(8, 38), 256, 0, stream>>>(
          emb, i_chars, f_part, f_h, W_ih, b_ih, W_hh, b_hh, f_gates, f_ctx);
      k_cell<<<BATCH, 256, 0, stream>>>(
          f_gates, f_ctx, W_proj, b_proj, b_phi, f_wphiT,
          f_c[s & 1], f_c[(s + 1) & 1], f_h, f_query, i_chars, out, s);
      k_att_s<<<dim3(BATCH, NCHUNK), 256, 0, stream>>>(kR, vR, f_query, f_part);
    }
  } else {
    // legacy path (proven): fused cell+att streaming over [T][B][K]
    k_att_fb<<<dim3(BATCH, NCHUNK), 256, 0, stream>>>(
        keys, values, f_gates, f_ctx, W_proj, b_proj, b_phi, f_wphiT,
        f_c[0], f_c[1], f_h, f_query, i_chars, f_part, out, -1);
    for (int s = 0; s < MAXLEN; ++s) {
      k_gates<<<dim3(8, 38), 256, 0, stream>>>(
          emb, i_chars, f_part, f_h, W_ih, b_ih, W_hh, b_hh, f_gates, f_ctx);
      k_att_fb<<<dim3(BATCH, NCHUNK), 256, 0, stream>>>(
          keys, values, f_gates, f_ctx, W_proj, b_proj, b_phi, f_wphiT,
          f_c[s & 1], f_c[(s + 1) & 1], f_h, f_query, i_chars, f_part, out, s);
    }
  }
}

// Round 2
// 55922.229 us; speedup vs baseline: 1.0138x; 1.0138x over previous
//
#include <hip/hip_runtime.h>
#include <math.h>

// ---- problem constants ----
constexpr int SEQ_T  = 2048;
constexpr int BATCH  = 128;
constexpr int KDIM   = 128;
constexpr int VDIM   = 128;
constexpr int EDIM   = 400;
constexpr int HDIM   = 300;
constexpr int GDIM   = 1200;    // 4*H
constexpr int NVOCAB = 33;
constexpr int MAXLEN = 500;
constexpr int SOS_TOK = 5;
constexpr int NCHUNK = 16;      // t-chunks per b
constexpr int CHT    = 128;     // t per chunk
constexpr int PROW   = 136;     // floats per partial row: accV[128], M, S, pad
constexpr long long NLOGITS = (long long)MAXLEN * BATCH * NVOCAB; // 2,112,000

// ---- ws float-element offsets ----
constexpr size_t OFF_H     = 0;        // 128*300
constexpr size_t OFF_C0    = 38400;    // 128*300 (ping)
constexpr size_t OFF_C1    = 76800;    // 128*300 (pong)
constexpr size_t OFF_GATES = 115200;   // 128*1200
constexpr size_t OFF_QUERY = 268800;   // 128*128
constexpr size_t OFF_CTX   = 285184;   // 128*128
constexpr size_t OFF_WPHIT = 301568;   // 300*128
constexpr size_t OFF_PART  = 339968;   // 2048*136
constexpr size_t OFF_CHARS = 618496;   // 128 int
// reordered [B][T][K] copies of keys/values (primary path)
constexpr size_t NKV       = (size_t)SEQ_T * BATCH * KDIM;   // 33,554,432 floats
constexpr size_t OFF_KEYSR = 655360;
constexpr size_t OFF_VALSR = OFF_KEYSR + NKV;
constexpr size_t WS_NEED_F = OFF_VALSR + NKV;                // ~271 MB

// ---------------------------------------------------------------------------
// async global->LDS DMA (16B per lane per issue). LDS dest is wave-uniform
// base; HW adds lane*16. Counted via vmcnt.
typedef __attribute__((address_space(3))) void lds_void_t;
typedef const __attribute__((address_space(1))) void glb_void_t;
__device__ __forceinline__ void dma16(const float* g, float* l) {
  __builtin_amdgcn_global_load_lds((glb_void_t*)g, (lds_void_t*)l, 16, 0, 0);
}

// stage one 32-t sub-tile (32*128 floats = 16KB, contiguous) into lbuf.
// 16 wave-instructions total = 4 per wave -> vmcnt +4 per wave.
__device__ __forceinline__ void stage32t(const float* __restrict__ src,
                                         float* lbuf, int wv, int ln) {
#pragma unroll
  for (int j = 0; j < 4; ++j) {
    const int off = ((j << 2) + wv) << 8;   // (j*4+wv)*256 floats
    dma16(src + off + ln * 4, lbuf + off);
  }
}

// raw barrier with LDS-visibility only (does NOT drain vmcnt -> keeps DMA
// prefetch in flight across the barrier; the whole point of this kernel).
#define LGKMBAR() do {                                          \
    asm volatile("s_waitcnt lgkmcnt(0)" ::: "memory");          \
    __builtin_amdgcn_s_barrier();                               \
    asm volatile("" ::: "memory");                              \
  } while (0)

// ---------------------------------------------------------------------------
// one-time: W_phi [128][300] -> W_phiT [300][128]
__global__ __launch_bounds__(256) void k_transpose(
    const float* __restrict__ W_phi, float* __restrict__ wphiT) {
  int i = blockIdx.x * 256 + threadIdx.x;
  if (i < HDIM * KDIM) {
    int j = i >> 7, kq = i & 127;
    wphiT[i] = W_phi[kq * HDIM + j];
  }
}

// one-time: h,c,chars init + initial query
__global__ __launch_bounds__(128) void k_init(
    const float* __restrict__ h0, const float* __restrict__ c0,
    const float* __restrict__ b_phi, const float* __restrict__ wphiT,
    float* __restrict__ h, float* __restrict__ c,
    float* __restrict__ query, int* __restrict__ chars_) {
  const int b = blockIdx.x;
  const int tid = threadIdx.x;
  for (int j = tid; j < HDIM; j += 128) {
    h[b * HDIM + j] = h0[j];
    c[b * HDIM + j] = c0[j];
  }
  {
    float q = b_phi[tid];
    for (int j = 0; j < HDIM; ++j) q += h0[j] * wphiT[j * KDIM + tid];
    query[b * KDIM + tid] = q;
  }
  if (tid == 0) chars_[b] = SOS_TOK;
}

// ---------------------------------------------------------------------------
// one-time: [T][B][128] -> [B][T][128] so each att block streams contiguously.
__global__ __launch_bounds__(256) void k_reorder(
    const float* __restrict__ src, float* __restrict__ dst) {
  const int b  = blockIdx.x;
  const int tt = blockIdx.y * 16;
  const int tid = threadIdx.x;
  for (int i = tid; i < 512; i += 256) {      // 16 t * 32 float4
    const int tl = i >> 5, k4 = i & 31;
    const size_t t = (size_t)(tt + tl);
    const float4 v = *(const float4*)(src + (t * BATCH + b) * KDIM + k4 * 4);
    *(float4*)(dst + ((size_t)b * SEQ_T + t) * KDIM + k4 * 4) = v;
  }
}

// ---------------------------------------------------------------------------
// k_att2: fused [cell -> logits/argmax (c0==0) -> query] + DMA-pipelined
// chunked attention over reordered [B][T][K] keys/values.
// grid 1024 (b = bid&127, c0 = bid>>7), 256 threads, 2 chunk-jobs per block
// (chunks c0 and c0+8, same b -> query computed once).
// Per job: 8 sub-tiles of 32 t (4 K then 4 V), double-buffered 16KB LDS DMA
// with counted vmcnt(4) + raw barriers -> ~64KB DMA in flight per CU.
// All arithmetic (dot order, reductions, accumulation order) is identical to
// the proven baseline -> bit-identical partials.
__global__ __launch_bounds__(256, 4) void k_att2(
    const float* __restrict__ keysR, const float* __restrict__ valsR,
    const float* __restrict__ gates, const float* __restrict__ ctx_g,
    const float* __restrict__ W_proj, const float* __restrict__ b_proj,
    const float* __restrict__ b_phi, const float* __restrict__ wphiT,
    const float* __restrict__ c_in, float* __restrict__ c_out,
    float* __restrict__ h, const float* __restrict__ query_g,
    int* __restrict__ chars_, float* __restrict__ partials,
    float* __restrict__ out, int step) {
  const int bid = blockIdx.x;
  const int b = bid & 127, c0 = bid >> 7;
  const int tid = threadIdx.x;
  const int wv = tid >> 6, ln = tid & 63;

  __shared__ __align__(16) float kbuf[2][32 * 128];  // 2 x 16KB double buffer
  __shared__ __align__(16) float scr[1056];  // preamble: hs_cat|logits ; jobs: redv
  __shared__ float qs[KDIM];
  __shared__ float e_s[CHT];
  __shared__ float att[CHT];
  __shared__ float red[8];

  float* hs_cat  = scr;          // 428 (preamble only)
  float* logit_s = scr + 428;    // 33  (preamble only)
  float* redv    = scr;          // 1056 (after preamble)

  // issue first K sub-tile DMA immediately; it lands under the preamble.
  {
    const float* kc0 = keysR + ((size_t)b * SEQ_T + (size_t)c0 * CHT) * KDIM;
    stage32t(kc0, kbuf[0], wv, ln);
  }

  if (step >= 0) {
    // ---- LSTM cell (redundant per block; identical fp ops -> identical h) ----
    for (int j = tid; j < HDIM; j += 256) {
      const float gi = gates[b * GDIM + j];
      const float gf = gates[b * GDIM + HDIM + j];
      const float gg = gates[b * GDIM + 2 * HDIM + j];
      const float go = gates[b * GDIM + 3 * HDIM + j];
      const float cc = c_in[b * HDIM + j];
      const float si = 1.f / (1.f + expf(-gi));
      const float sf = 1.f / (1.f + expf(-gf));
      const float so = 1.f / (1.f + expf(-go));
      const float cn = sf * cc + si * tanhf(gg);
      const float hn = so * tanhf(cn);
      hs_cat[j] = hn;
      if (c0 == 0) { c_out[b * HDIM + j] = cn; h[b * HDIM + j] = hn; }
    }
    if (c0 == 0 && tid < VDIM) hs_cat[HDIM + tid] = ctx_g[b * VDIM + tid];
    LGKMBAR();
    if (c0 == 0) {
      // ---- logits + argmax + emit (single writer: c0==0 blocks) ----
      const int w = tid >> 6, l = tid & 63;
      for (int j = w; j < NVOCAB; j += 4) {
        float p = 0.f;
        for (int e = l; e < HDIM + VDIM; e += 64) p += hs_cat[e] * W_proj[j * 428 + e];
        p += __shfl_xor(p, 1); p += __shfl_xor(p, 2); p += __shfl_xor(p, 4);
        p += __shfl_xor(p, 8); p += __shfl_xor(p, 16); p += __shfl_xor(p, 32);
        if (l == 0) logit_s[j] = p + b_proj[j];
      }
      LGKMBAR();
      if (tid < NVOCAB) out[((size_t)step * BATCH + b) * NVOCAB + tid] = logit_s[tid];
      if (tid == 0) {
        float best = logit_s[0];
        int bi = 0;
        for (int j = 1; j < NVOCAB; ++j)
          if (logit_s[j] > best) { best = logit_s[j]; bi = j; }  // np first-max
        chars_[b] = bi;
        out[NLOGITS + (size_t)step * BATCH + b] = (float)bi;
      }
    }
    // ---- query from h_new ----
    if (tid < KDIM) {
      float q0 = b_phi[tid], q1 = 0.f;
      for (int j = 0; j < HDIM; j += 2) {
        q0 += hs_cat[j]     * wphiT[j * KDIM + tid];
        q1 += hs_cat[j + 1] * wphiT[(j + 1) * KDIM + tid];
      }
      qs[tid] = q0 + q1;
    }
  } else {
    if (tid < KDIM) qs[tid] = query_g[b * KDIM + tid];
  }
  // qs visibility: covered by iter-0 barrier below (lgkmcnt(0) + barrier).

  for (int job = 0; job < 2; ++job) {
    const int chunk = c0 + (job << 3);
    const float* kc = keysR + ((size_t)b * SEQ_T + (size_t)chunk * CHT) * KDIM;
    const float* vc = valsR + ((size_t)b * SEQ_T + (size_t)chunk * CHT) * KDIM;
    float4 acc = make_float4(0.f, 0.f, 0.f, 0.f);
    float Mj = 0.f, Sj = 0.f;

    for (int u = 0; u < 8; ++u) {
      // ---- issue next sub-tile DMA, then wait for current (counted vmcnt) ----
      if (u < 7) {
        const float* nsrc = (u < 3) ? kc + (u + 1) * 4096 : vc + (u - 3) * 4096;
        stage32t(nsrc, kbuf[(u + 1) & 1], wv, ln);
        asm volatile("s_waitcnt vmcnt(4) lgkmcnt(0)" ::: "memory");
      } else if (job == 0) {
        // pipeline job2's first K sub-tile during job1's last V iteration
        const float* nkc = keysR + ((size_t)b * SEQ_T + (size_t)(c0 + 8) * CHT) * KDIM;
        stage32t(nkc, kbuf[0], wv, ln);
        asm volatile("s_waitcnt vmcnt(4) lgkmcnt(0)" ::: "memory");
      } else {
        asm volatile("s_waitcnt vmcnt(0) lgkmcnt(0)" ::: "memory");
      }
      __builtin_amdgcn_s_barrier();
      asm volatile("" ::: "memory");

      const float* kb = kbuf[u & 1];
      if (u < 4) {
        // ---- energies for 32 t from LDS (identical dot + 5-shfl reduce) ----
        const int hw = tid >> 5, l32 = tid & 31;
        const float4 q4 = *(const float4*)(qs + l32 * 4);
#pragma unroll
        for (int i = 0; i < 4; ++i) {
          const int tl = (hw << 2) + i;
          const float4 kv = *(const float4*)(kb + tl * 128 + l32 * 4);
          float p = q4.x * kv.x + q4.y * kv.y + q4.z * kv.z + q4.w * kv.w;
          p += __shfl_xor(p, 1); p += __shfl_xor(p, 2); p += __shfl_xor(p, 4);
          p += __shfl_xor(p, 8); p += __shfl_xor(p, 16);
          if (l32 == 0) e_s[(u << 5) + tl] = p;
        }
      } else {
        if (u == 4) {
          // ---- chunk softmax stats (verbatim baseline) ----
          float mm = (tid < CHT) ? e_s[tid] : -INFINITY;
          for (int off = 32; off; off >>= 1) mm = fmaxf(mm, __shfl_xor(mm, off));
          if ((tid & 63) == 0) red[tid >> 6] = mm;
          LGKMBAR();
          Mj = fmaxf(fmaxf(red[0], red[1]), fmaxf(red[2], red[3]));
          float ex = 0.f;
          if (tid < CHT) { ex = expf(e_s[tid] - Mj); att[tid] = ex; }
          for (int off = 32; off; off >>= 1) ex += __shfl_xor(ex, off);
          if ((tid & 63) == 0) red[4 + (tid >> 6)] = ex;
          LGKMBAR();
          Sj = red[4] + red[5] + red[6] + red[7];
        }
        // ---- weighted V accumulation (identical order: t = i*8+tsub asc.) ----
        const int s = u - 4;
        const int v4 = tid & 31, tsub = tid >> 5;
#pragma unroll
        for (int i = 0; i < 4; ++i) {
          const int tl = (i << 3) + tsub;
          const float a = att[(s << 5) + tl];
          const float4 val = *(const float4*)(kb + tl * 128 + v4 * 4);
          acc.x += a * val.x; acc.y += a * val.y;
          acc.z += a * val.z; acc.w += a * val.w;
        }
      }
      asm volatile("s_waitcnt lgkmcnt(0)" ::: "memory");
      __builtin_amdgcn_s_barrier();
      asm volatile("" ::: "memory");
    }

    // ---- cross-thread combine (verbatim baseline; redv in scr) ----
    {
      const int v4 = tid & 31, tsub = tid >> 5;
      *(float4*)(redv + (tsub * 33 + v4) * 4) = acc;
    }
    LGKMBAR();
    const size_t r = (size_t)b * NCHUNK + chunk;
    if (tid < 32) {
      float4 s4 = *(const float4*)(redv + tid * 4);
      for (int p = 1; p < 8; ++p) {               // fixed order -> deterministic
        const float4 rr = *(const float4*)(redv + (p * 33 + tid) * 4);
        s4.x += rr.x; s4.y += rr.y; s4.z += rr.z; s4.w += rr.w;
      }
      *(float4*)(partials + r * PROW + tid * 4) = s4;
    }
    if (tid == 0) {
      partials[r * PROW + 128] = Mj;
      partials[r * PROW + 129] = Sj;
    }
    __builtin_amdgcn_s_barrier();   // redv reads done before job2 reuse
    asm volatile("" ::: "memory");
  }
}

// ---------------------------------------------------------------------------
// k_gates: [combine partials -> ctx] + gates GEMM (proven, unchanged).
__global__ __launch_bounds__(256) void k_gates(
    const float* __restrict__ emb, const int* __restrict__ chars_,
    const float* __restrict__ partials, const float* __restrict__ h,
    const float* __restrict__ W_ih, const float* __restrict__ b_ih,
    const float* __restrict__ W_hh, const float* __restrict__ b_hh,
    float* __restrict__ gates, float* __restrict__ ctx_g) {
  const int bT = blockIdx.x * 16;
  const int jT = blockIdx.y * 32;
  const int tid = threadIdx.x;
  __shared__ float Xs[16 * 836];
  __shared__ float ctxs[16 * 128];
  {
    const int bl = tid >> 4, l16 = tid & 15;
    const int bg = bT + bl;
    const float* pb = partials + (size_t)bg * NCHUNK * PROW;
    float M = -INFINITY;
    for (int ci = 0; ci < NCHUNK; ++ci) M = fmaxf(M, pb[ci * PROW + 128]);
    float den = 0.f;
    float4 n0 = make_float4(0.f, 0.f, 0.f, 0.f);
    float4 n1 = make_float4(0.f, 0.f, 0.f, 0.f);
    for (int ci = 0; ci < NCHUNK; ++ci) {
      const float w = expf(pb[ci * PROW + 128] - M);
      den += w * pb[ci * PROW + 129];
      const float4 a0 = *(const float4*)(pb + ci * PROW + l16 * 8);
      const float4 a1 = *(const float4*)(pb + ci * PROW + l16 * 8 + 4);
      n0.x += w * a0.x; n0.y += w * a0.y; n0.z += w * a0.z; n0.w += w * a0.w;
      n1.x += w * a1.x; n1.y += w * a1.y; n1.z += w * a1.z; n1.w += w * a1.w;
    }
    const float inv = 1.f / den;
    n0.x *= inv; n0.y *= inv; n0.z *= inv; n0.w *= inv;
    n1.x *= inv; n1.y *= inv; n1.z *= inv; n1.w *= inv;
    *(float4*)(ctxs + bl * 128 + l16 * 8)     = n0;
    *(float4*)(ctxs + bl * 128 + l16 * 8 + 4) = n1;
    if (blockIdx.y == 0) {
      *(float4*)(ctx_g + bg * 128 + l16 * 8)     = n0;
      *(float4*)(ctx_g + bg * 128 + l16 * 8 + 4) = n1;
    }
  }
  __syncthreads();
  for (int bb = 0; bb < 16; ++bb) {
    const int bg = bT + bb;
    const int ch = chars_[bg];
    for (int k = tid; k < 832; k += 256) {
      float x;
      if (k < EDIM)      x = emb[ch * EDIM + k];
      else if (k < 528)  x = ctxs[bb * 128 + (k - EDIM)];
      else if (k < 828)  x = h[bg * HDIM + (k - 528)];
      else               x = 0.f;
      Xs[bb * 836 + k] = x;
    }
  }
  __syncthreads();
  const int bLoc = tid & 15;
  const int jLoc = tid >> 4;
  const int j0 = jT + jLoc * 2;
  if (j0 >= GDIM) return;
  const int j1 = j0 + 1;
  const int bg = bT + bLoc;
  float acc0 = 0.f, acc1 = 0.f;
  const float4* xr = (const float4*)(Xs + bLoc * 836);
  {
    const float4* w0 = (const float4*)(W_ih + (size_t)j0 * 528);
    const float4* w1 = (const float4*)(W_ih + (size_t)j1 * 528);
    for (int k4 = 0; k4 < 132; ++k4) {
      const float4 xv = xr[k4];
      const float4 a = w0[k4];
      const float4 bv = w1[k4];
      acc0 += xv.x * a.x + xv.y * a.y + xv.z * a.z + xv.w * a.w;
      acc1 += xv.x * bv.x + xv.y * bv.y + xv.z * bv.z + xv.w * bv.w;
    }
  }
  {
    const float4* xh = (const float4*)(Xs + bLoc * 836 + 528);
    const float4* g0 = (const float4*)(W_hh + (size_t)j0 * HDIM);
    const float4* g1 = (const float4*)(W_hh + (size_t)j1 * HDIM);
    for (int k4 = 0; k4 < 75; ++k4) {
      const float4 xv = xh[k4];
      const float4 a = g0[k4];
      const float4 bv = g1[k4];
      acc0 += xv.x * a.x + xv.y * a.y + xv.z * a.z + xv.w * a.w;
      acc1 += xv.x * bv.x + xv.y * bv.y + xv.z * bv.z + xv.w * bv.w;
    }
  }
  gates[bg * GDIM + j0] = acc0 + b_ih[j0] + b_hh[j0];
  gates[bg * GDIM + j1] = acc1 + b_ih[j1] + b_hh[j1];
}

// ---------------------------------------------------------------------------
// Legacy fused k_att (fallback when workspace can't hold reordered copies).
__global__ __launch_bounds__(256) void k_att_fb(
    const float* __restrict__ keys, const float* __restrict__ values,
    const float* __restrict__ gates, const float* __restrict__ ctx_g,
    const float* __restrict__ W_proj, const float* __restrict__ b_proj,
    const float* __restrict__ b_phi, const float* __restrict__ wphiT,
    const float* __restrict__ c_in, float* __restrict__ c_out,
    float* __restrict__ h, const float* __restrict__ query_g,
    int* __restrict__ chars_, float* __restrict__ partials,
    float* __restrict__ out, int step) {
  const int b = blockIdx.x, chunk = blockIdx.y, tid = threadIdx.x;
  __shared__ float hs_cat[HDIM + VDIM];
  __shared__ float logit_s[NVOCAB];
  __shared__ float qs[KDIM];
  __shared__ float e_s[CHT];
  __shared__ float att[CHT];
  __shared__ float red[8];
  __shared__ __align__(16) float redv[8 * 33 * 4];

  if (step >= 0) {
    for (int j = tid; j < HDIM; j += 256) {
      const float gi = gates[b * GDIM + j];
      const float gf = gates[b * GDIM + HDIM + j];
      const float gg = gates[b * GDIM + 2 * HDIM + j];
      const float go = gates[b * GDIM + 3 * HDIM + j];
      const float cc = c_in[b * HDIM + j];
      const float si = 1.f / (1.f + expf(-gi));
      const float sf = 1.f / (1.f + expf(-gf));
      const float so = 1.f / (1.f + expf(-go));
      const float cn = sf * cc + si * tanhf(gg);
      const float hn = so * tanhf(cn);
      hs_cat[j] = hn;
      if (chunk == 0) { c_out[b * HDIM + j] = cn; h[b * HDIM + j] = hn; }
    }
    if (chunk == 0 && tid < VDIM) hs_cat[HDIM + tid] = ctx_g[b * VDIM + tid];
    __syncthreads();
    if (chunk == 0) {
      const int w = tid >> 6, l = tid & 63;
      for (int j = w; j < NVOCAB; j += 4) {
        float p = 0.f;
        for (int e = l; e < HDIM + VDIM; e += 64) p += hs_cat[e] * W_proj[j * 428 + e];
        p += __shfl_xor(p, 1); p += __shfl_xor(p, 2); p += __shfl_xor(p, 4);
        p += __shfl_xor(p, 8); p += __shfl_xor(p, 16); p += __shfl_xor(p, 32);
        if (l == 0) logit_s[j] = p + b_proj[j];
      }
      __syncthreads();
      if (tid < NVOCAB) out[((size_t)step * BATCH + b) * NVOCAB + tid] = logit_s[tid];
      if (tid == 0) {
        float best = logit_s[0];
        int bi = 0;
        for (int j = 1; j < NVOCAB; ++j)
          if (logit_s[j] > best) { best = logit_s[j]; bi = j; }
        chars_[b] = bi;
        out[NLOGITS + (size_t)step * BATCH + b] = (float)bi;
      }
    }
    if (tid < KDIM) {
      float q = b_phi[tid];
      for (int j = 0; j < HDIM; ++j) q += hs_cat[j] * wphiT[j * KDIM + tid];
      qs[tid] = q;
    }
  } else {
    if (tid < KDIM) qs[tid] = query_g[b * KDIM + tid];
  }
  __syncthreads();

  const int wave = tid >> 6, lane = tid & 63;
  const int half = lane >> 5, l32 = lane & 31;
  {
    const float4 q4 = *(const float4*)(qs + l32 * 4);
    const int tl0 = wave * 32;
    for (int i = 0; i < 16; ++i) {
      const int tl = tl0 + 2 * i + half;
      const int t = chunk * CHT + tl;
      const float4 kv = *(const float4*)(keys + ((size_t)t * BATCH + b) * KDIM + l32 * 4);
      float p = q4.x * kv.x + q4.y * kv.y + q4.z * kv.z + q4.w * kv.w;
      p += __shfl_xor(p, 1); p += __shfl_xor(p, 2); p += __shfl_xor(p, 4);
      p += __shfl_xor(p, 8); p += __shfl_xor(p, 16);
      if (l32 == 0) e_s[tl] = p;
    }
  }
  __syncthreads();

  float m = (tid < CHT) ? e_s[tid] : -INFINITY;
  for (int off = 32; off; off >>= 1) m = fmaxf(m, __shfl_xor(m, off));
  if ((tid & 63) == 0) red[tid >> 6] = m;
  __syncthreads();
  const float M = fmaxf(fmaxf(red[0], red[1]), fmaxf(red[2], red[3]));
  float ex = 0.f;
  if (tid < CHT) { ex = expf(e_s[tid] - M); att[tid] = ex; }
  for (int off = 32; off; off >>= 1) ex += __shfl_xor(ex, off);
  if ((tid & 63) == 0) red[4 + (tid >> 6)] = ex;
  __syncthreads();
  const float S = red[4] + red[5] + red[6] + red[7];

  const int v4 = tid & 31, tsub = tid >> 5;
  float4 acc = make_float4(0.f, 0.f, 0.f, 0.f);
  const float* vb = values + (size_t)b * VDIM + v4 * 4;
  for (int i = 0; i < 16; ++i) {
    const int tl = i * 8 + tsub;
    const float a = att[tl];
    const float4 val = *(const float4*)(vb + (size_t)(chunk * CHT + tl) * BATCH * VDIM);
    acc.x += a * val.x; acc.y += a * val.y; acc.z += a * val.z; acc.w += a * val.w;
  }
  *(float4*)(redv + (tsub * 33 + v4) * 4) = acc;
  __syncthreads();
  const size_t r = (size_t)b * NCHUNK + chunk;
  if (tid < 32) {
    float4 s4 = *(const float4*)(redv + tid * 4);
    for (int p = 1; p < 8; ++p) {
      const float4 rr = *(const float4*)(redv + (p * 33 + tid) * 4);
      s4.x += rr.x; s4.y += rr.y; s4.z += rr.z; s4.w += rr.w;
    }
    *(float4*)(partials + r * PROW + tid * 4) = s4;
  }
  if (tid == 0) {
    partials[r * PROW + 128] = M;
    partials[r * PROW + 129] = S;
  }
}

// ---------------------------------------------------------------------------
extern "C" void kernel_launch(void* const* d_in, const int* in_sizes, int n_in,
                              void* d_out, int out_size, void* d_ws, size_t ws_size,
                              hipStream_t stream) {
  (void)in_sizes; (void)n_in; (void)out_size;
  const float* keys   = (const float*)d_in[0];
  const float* values = (const float*)d_in[1];
  const float* emb    = (const float*)d_in[2];
  const float* W_phi  = (const float*)d_in[3];
  const float* b_phi  = (const float*)d_in[4];
  const float* W_ih   = (const float*)d_in[5];
  const float* b_ih   = (const float*)d_in[6];
  const float* W_hh   = (const float*)d_in[7];
  const float* b_hh   = (const float*)d_in[8];
  const float* W_proj = (const float*)d_in[9];
  const float* b_proj = (const float*)d_in[10];
  const float* h0     = (const float*)d_in[11];
  const float* c0     = (const float*)d_in[12];
  float* out = (float*)d_out;

  float* F = (float*)d_ws;
  float* f_h     = F + OFF_H;
  float* f_c[2]  = {F + OFF_C0, F + OFF_C1};
  float* f_gates = F + OFF_GATES;
  float* f_query = F + OFF_QUERY;
  float* f_ctx   = F + OFF_CTX;
  float* f_wphiT = F + OFF_WPHIT;
  float* f_part  = F + OFF_PART;
  int*   i_chars = (int*)(F + OFF_CHARS);

  k_transpose<<<150, 256, 0, stream>>>(W_phi, f_wphiT);
  k_init<<<BATCH, 128, 0, stream>>>(h0, c0, b_phi, f_wphiT, f_h, f_c[0],
                                    f_query, i_chars);

  const bool big = ws_size >= WS_NEED_F * sizeof(float);
  if (big) {
    float* kR = F + OFF_KEYSR;
    float* vR = F + OFF_VALSR;
    k_reorder<<<dim3(BATCH, SEQ_T / 16), 256, 0, stream>>>(keys, kR);
    k_reorder<<<dim3(BATCH, SEQ_T / 16), 256, 0, stream>>>(values, vR);
    // initial attend(h0): query from k_init
    k_att2<<<1024, 256, 0, stream>>>(
        kR, vR, f_gates, f_ctx, W_proj, b_proj, b_phi, f_wphiT,
        f_c[0], f_c[1], f_h, f_query, i_chars, f_part, out, -1);
    for (int s = 0; s < MAXLEN; ++s) {
      k_gates<<<dim3(8, 38), 256, 0, stream>>>(
          emb, i_chars, f_part, f_h, W_ih, b_ih, W_hh, b_hh, f_gates, f_ctx);
      k_att2<<<1024, 256, 0, stream>>>(
          kR, vR, f_gates, f_ctx, W_proj, b_proj, b_phi, f_wphiT,
          f_c[s & 1], f_c[(s + 1) & 1], f_h, f_query, i_chars, f_part, out, s);
    }
  } else {
    // legacy path (proven): fused cell+att streaming over [T][B][K]
    k_att_fb<<<dim3(BATCH, NCHUNK), 256, 0, stream>>>(
        keys, values, f_gates, f_ctx, W_proj, b_proj, b_phi, f_wphiT,
        f_c[0], f_c[1], f_h, f_query, i_chars, f_part, out, -1);
    for (int s = 0; s < MAXLEN; ++s) {
      k_gates<<<dim3(8, 38), 256, 0, stream>>>(
          emb, i_chars, f_part, f_h, W_ih, b_ih, W_hh, b_hh, f_gates, f_ctx);
      k_att_fb<<<dim3(BATCH, NCHUNK), 256, 0, stream>>>(
          keys, values, f_gates, f_ctx, W_proj, b_proj, b_phi, f_wphiT,
          f_c[s & 1], f_c[(s + 1) & 1], f_h, f_query, i_chars, f_part, out, s);
    }
  }
}

// Round 3
// 49184.512 us; speedup vs baseline: 1.1527x; 1.1370x over previous
//
#include <hip/hip_runtime.h>
#include <hip/hip_fp16.h>
#include <math.h>

// ---- problem constants ----
constexpr int SEQ_T  = 2048;
constexpr int BATCH  = 128;
constexpr int KDIM   = 128;
constexpr int VDIM   = 128;
constexpr int EDIM   = 400;
constexpr int HDIM   = 300;
constexpr int GDIM   = 1200;    // 4*H
constexpr int NVOCAB = 33;
constexpr int MAXLEN = 500;
constexpr int SOS_TOK = 5;
constexpr int NCHUNK = 16;      // t-chunks per b
constexpr int CHT    = 128;     // t per chunk
constexpr int PROW   = 136;     // floats per partial row: accV[128], M, S, pad
constexpr long long NLOGITS = (long long)MAXLEN * BATCH * NVOCAB; // 2,112,000

// ---- ws float-element offsets ----
constexpr size_t OFF_H     = 0;        // 128*300
constexpr size_t OFF_C0    = 38400;    // 128*300 (ping)
constexpr size_t OFF_C1    = 76800;    // 128*300 (pong)
constexpr size_t OFF_GATES = 115200;   // 128*1200
constexpr size_t OFF_QUERY = 268800;   // 128*128
constexpr size_t OFF_CTX   = 285184;   // 128*128
constexpr size_t OFF_WPHIT = 301568;   // 300*128
constexpr size_t OFF_PART  = 339968;   // 2048*136
constexpr size_t OFF_CHARS = 618496;   // 128 int
// fp16 [B][T][K] copies of keys/values (primary path). keysH occupies
// NKV halves = NKV/2 float slots; valsH right after.
constexpr size_t NKV       = (size_t)SEQ_T * BATCH * KDIM;   // 33,554,432 elems
constexpr size_t OFF_KVH   = 655360;                          // float idx
constexpr size_t WS_NEED_F = OFF_KVH + NKV;                   // ~137 MB total

// ---------------------------------------------------------------------------
// one-time: W_phi [128][300] -> W_phiT [300][128]
__global__ __launch_bounds__(256) void k_transpose(
    const float* __restrict__ W_phi, float* __restrict__ wphiT) {
  int i = blockIdx.x * 256 + threadIdx.x;
  if (i < HDIM * KDIM) {
    int j = i >> 7, kq = i & 127;
    wphiT[i] = W_phi[kq * HDIM + j];
  }
}

// one-time: h,c,chars init + initial query
__global__ __launch_bounds__(128) void k_init(
    const float* __restrict__ h0, const float* __restrict__ c0,
    const float* __restrict__ b_phi, const float* __restrict__ wphiT,
    float* __restrict__ h, float* __restrict__ c,
    float* __restrict__ query, int* __restrict__ chars_) {
  const int b = blockIdx.x;
  const int tid = threadIdx.x;
  for (int j = tid; j < HDIM; j += 128) {
    h[b * HDIM + j] = h0[j];
    c[b * HDIM + j] = c0[j];
  }
  {
    float q = b_phi[tid];
    for (int j = 0; j < HDIM; ++j) q += h0[j] * wphiT[j * KDIM + tid];
    query[b * KDIM + tid] = q;
  }
  if (tid == 0) chars_[b] = SOS_TOK;
}

// ---------------------------------------------------------------------------
// one-time: f32 [T][B][128] -> f16 [B][T][128]. RN rounding.
// grid (128 b, 128 t-tiles of 16), 256 threads.
__global__ __launch_bounds__(256) void k_tohalf(
    const float* __restrict__ src, __half* __restrict__ dst) {
  const int b  = blockIdx.x;
  const int tt = blockIdx.y * 16;
  const int tid = threadIdx.x;
  for (int i = tid; i < 512; i += 256) {      // 16 t * 32 float4
    const int tl = i >> 5, k4 = i & 31;
    const size_t t = (size_t)(tt + tl);
    const float4 v = *(const float4*)(src + (t * BATCH + b) * KDIM + k4 * 4);
    const __half2 h0 = __floats2half2_rn(v.x, v.y);
    const __half2 h1 = __floats2half2_rn(v.z, v.w);
    uint2 pk;
    pk.x = *(const unsigned int*)&h0;
    pk.y = *(const unsigned int*)&h1;
    *(uint2*)(dst + ((size_t)b * SEQ_T + t) * KDIM + k4 * 4) = pk;
  }
}

// ---------------------------------------------------------------------------
// k_att3: fused [cell -> logits/argmax (chunk0) -> query] + attention over
// fp16 [B][T][128] keys/values. K+V total 134 MB -> Infinity-Cache-resident
// across steps, so the streaming phase reads from L3, not HBM.
// grid (128 b, 16 chunk), 256 threads.
// Energy: 16-lane groups (8 dims/lane, f32 math after cvt), 4 t per wave
// per round, 8 rounds. Softmax stats verbatim baseline. V: 16 dim-groups x
// 16 t-lanes, f32 accumulate, fixed-order LDS reduction -> partials f32
// (PROW layout unchanged -> k_gates untouched).
__global__ __launch_bounds__(256) void k_att3(
    const __half* __restrict__ keysH, const __half* __restrict__ valsH,
    const float* __restrict__ gates, const float* __restrict__ ctx_g,
    const float* __restrict__ W_proj, const float* __restrict__ b_proj,
    const float* __restrict__ b_phi, const float* __restrict__ wphiT,
    const float* __restrict__ c_in, float* __restrict__ c_out,
    float* __restrict__ h, const float* __restrict__ query_g,
    int* __restrict__ chars_, float* __restrict__ partials,
    float* __restrict__ out, int step) {
  const int b = blockIdx.x, chunk = blockIdx.y, tid = threadIdx.x;
  __shared__ __align__(16) float scr[2048];   // preamble: hs_cat|logits ; V: redv
  __shared__ float qs[KDIM];
  __shared__ float e_s[CHT];
  __shared__ float att[CHT];
  __shared__ float red[8];

  float* hs_cat  = scr;          // 428 (preamble only)
  float* logit_s = scr + 428;    // 33  (preamble only)
  float* redv    = scr;          // 2048 = 16 tsub x 128 dim (V phase)

  if (step >= 0) {
    // ---- LSTM cell (redundant per chunk; identical fp ops -> identical h) ----
    for (int j = tid; j < HDIM; j += 256) {
      const float gi = gates[b * GDIM + j];
      const float gf = gates[b * GDIM + HDIM + j];
      const float gg = gates[b * GDIM + 2 * HDIM + j];
      const float go = gates[b * GDIM + 3 * HDIM + j];
      const float cc = c_in[b * HDIM + j];
      const float si = 1.f / (1.f + expf(-gi));
      const float sf = 1.f / (1.f + expf(-gf));
      const float so = 1.f / (1.f + expf(-go));
      const float cn = sf * cc + si * tanhf(gg);
      const float hn = so * tanhf(cn);
      hs_cat[j] = hn;
      if (chunk == 0) { c_out[b * HDIM + j] = cn; h[b * HDIM + j] = hn; }
    }
    if (chunk == 0 && tid < VDIM) hs_cat[HDIM + tid] = ctx_g[b * VDIM + tid];
    __syncthreads();
    if (chunk == 0) {
      // ---- logits + argmax + emit (single writer: chunk0) ----
      const int w = tid >> 6, l = tid & 63;
      for (int j = w; j < NVOCAB; j += 4) {
        float p = 0.f;
        for (int e = l; e < HDIM + VDIM; e += 64) p += hs_cat[e] * W_proj[j * 428 + e];
        p += __shfl_xor(p, 1); p += __shfl_xor(p, 2); p += __shfl_xor(p, 4);
        p += __shfl_xor(p, 8); p += __shfl_xor(p, 16); p += __shfl_xor(p, 32);
        if (l == 0) logit_s[j] = p + b_proj[j];
      }
      __syncthreads();
      if (tid < NVOCAB) out[((size_t)step * BATCH + b) * NVOCAB + tid] = logit_s[tid];
      if (tid == 0) {
        float best = logit_s[0];
        int bi = 0;
        for (int j = 1; j < NVOCAB; ++j)
          if (logit_s[j] > best) { best = logit_s[j]; bi = j; }  // np first-max
        chars_[b] = bi;
        out[NLOGITS + (size_t)step * BATCH + b] = (float)bi;
      }
    }
    // ---- query from h_new ----
    if (tid < KDIM) {
      float q0 = b_phi[tid], q1 = 0.f;
      for (int j = 0; j < HDIM; j += 2) {
        q0 += hs_cat[j]     * wphiT[j * KDIM + tid];
        q1 += hs_cat[j + 1] * wphiT[(j + 1) * KDIM + tid];
      }
      qs[tid] = q0 + q1;
    }
  } else {
    if (tid < KDIM) qs[tid] = query_g[b * KDIM + tid];
  }
  __syncthreads();

  // ---- energy over this chunk's 128 t (fp16 K, f32 math) ----
  {
    const int wv = tid >> 6, ln = tid & 63;
    const int tq = ln >> 4, l16 = ln & 15;
    float qf[8];
#pragma unroll
    for (int j = 0; j < 8; ++j) qf[j] = qs[l16 * 8 + j];
    const __half* kb = keysH + ((size_t)b * SEQ_T + (size_t)chunk * CHT) * KDIM;
#pragma unroll
    for (int r = 0; r < 8; ++r) {
      const int tl = r * 16 + wv * 4 + tq;
      const uint4 raw = *(const uint4*)(kb + (size_t)tl * KDIM + l16 * 8);
      union { uint4 u; __half2 h[4]; } c; c.u = raw;
      const float2 f0 = __half22float2(c.h[0]);
      const float2 f1 = __half22float2(c.h[1]);
      const float2 f2 = __half22float2(c.h[2]);
      const float2 f3 = __half22float2(c.h[3]);
      float p = qf[0] * f0.x + qf[1] * f0.y + qf[2] * f1.x + qf[3] * f1.y
              + qf[4] * f2.x + qf[5] * f2.y + qf[6] * f3.x + qf[7] * f3.y;
      p += __shfl_xor(p, 1); p += __shfl_xor(p, 2);
      p += __shfl_xor(p, 4); p += __shfl_xor(p, 8);
      if (l16 == 0) e_s[tl] = p;
    }
  }
  __syncthreads();

  // ---- chunk-local softmax stats (M_c, S_c) — verbatim baseline ----
  float m = (tid < CHT) ? e_s[tid] : -INFINITY;
  for (int off = 32; off; off >>= 1) m = fmaxf(m, __shfl_xor(m, off));
  if ((tid & 63) == 0) red[tid >> 6] = m;
  __syncthreads();
  const float M = fmaxf(fmaxf(red[0], red[1]), fmaxf(red[2], red[3]));
  float ex = 0.f;
  if (tid < CHT) { ex = expf(e_s[tid] - M); att[tid] = ex; }
  for (int off = 32; off; off >>= 1) ex += __shfl_xor(ex, off);
  if ((tid & 63) == 0) red[4 + (tid >> 6)] = ex;
  __syncthreads();
  const float S = red[4] + red[5] + red[6] + red[7];

  // ---- unnormalized weighted V accumulation (fp16 V, f32 accumulate) ----
  {
    const int d16 = tid & 15, tsub = tid >> 4;   // 16 dim-groups x 16 t-lanes
    const __half* vb = valsH + ((size_t)b * SEQ_T + (size_t)chunk * CHT) * KDIM;
    float av[8] = {0.f, 0.f, 0.f, 0.f, 0.f, 0.f, 0.f, 0.f};
#pragma unroll
    for (int r = 0; r < 8; ++r) {
      const int tl = r * 16 + tsub;
      const float a = att[tl];
      const uint4 raw = *(const uint4*)(vb + (size_t)tl * KDIM + d16 * 8);
      union { uint4 u; __half2 h[4]; } c; c.u = raw;
      const float2 f0 = __half22float2(c.h[0]);
      const float2 f1 = __half22float2(c.h[1]);
      const float2 f2 = __half22float2(c.h[2]);
      const float2 f3 = __half22float2(c.h[3]);
      av[0] += a * f0.x; av[1] += a * f0.y; av[2] += a * f1.x; av[3] += a * f1.y;
      av[4] += a * f2.x; av[5] += a * f2.y; av[6] += a * f3.x; av[7] += a * f3.y;
    }
    __syncthreads();   // preamble/scr reuse & att reads done
    *(float4*)(redv + tsub * 128 + d16 * 8)     = make_float4(av[0], av[1], av[2], av[3]);
    *(float4*)(redv + tsub * 128 + d16 * 8 + 4) = make_float4(av[4], av[5], av[6], av[7]);
  }
  __syncthreads();
  const size_t rrow = (size_t)b * NCHUNK + chunk;
  if (tid < 128) {
    float sacc = 0.f;
#pragma unroll
    for (int p = 0; p < 16; ++p) sacc += redv[p * 128 + tid];  // fixed order
    partials[rrow * PROW + tid] = sacc;
  }
  if (tid == 0) {
    partials[rrow * PROW + 128] = M;
    partials[rrow * PROW + 129] = S;
  }
}

// ---------------------------------------------------------------------------
// k_gates: [combine partials -> ctx] + gates GEMM (proven geometry; only
// change: unroll pragmas on the two K-loops — FP order preserved).
__global__ __launch_bounds__(256) void k_gates(
    const float* __restrict__ emb, const int* __restrict__ chars_,
    const float* __restrict__ partials, const float* __restrict__ h,
    const float* __restrict__ W_ih, const float* __restrict__ b_ih,
    const float* __restrict__ W_hh, const float* __restrict__ b_hh,
    float* __restrict__ gates, float* __restrict__ ctx_g) {
  const int bT = blockIdx.x * 16;
  const int jT = blockIdx.y * 32;
  const int tid = threadIdx.x;
  __shared__ float Xs[16 * 836];
  __shared__ float ctxs[16 * 128];
  {
    const int bl = tid >> 4, l16 = tid & 15;
    const int bg = bT + bl;
    const float* pb = partials + (size_t)bg * NCHUNK * PROW;
    float M = -INFINITY;
    for (int ci = 0; ci < NCHUNK; ++ci) M = fmaxf(M, pb[ci * PROW + 128]);
    float den = 0.f;
    float4 n0 = make_float4(0.f, 0.f, 0.f, 0.f);
    float4 n1 = make_float4(0.f, 0.f, 0.f, 0.f);
    for (int ci = 0; ci < NCHUNK; ++ci) {
      const float w = expf(pb[ci * PROW + 128] - M);
      den += w * pb[ci * PROW + 129];
      const float4 a0 = *(const float4*)(pb + ci * PROW + l16 * 8);
      const float4 a1 = *(const float4*)(pb + ci * PROW + l16 * 8 + 4);
      n0.x += w * a0.x; n0.y += w * a0.y; n0.z += w * a0.z; n0.w += w * a0.w;
      n1.x += w * a1.x; n1.y += w * a1.y; n1.z += w * a1.z; n1.w += w * a1.w;
    }
    const float inv = 1.f / den;
    n0.x *= inv; n0.y *= inv; n0.z *= inv; n0.w *= inv;
    n1.x *= inv; n1.y *= inv; n1.z *= inv; n1.w *= inv;
    *(float4*)(ctxs + bl * 128 + l16 * 8)     = n0;
    *(float4*)(ctxs + bl * 128 + l16 * 8 + 4) = n1;
    if (blockIdx.y == 0) {
      *(float4*)(ctx_g + bg * 128 + l16 * 8)     = n0;
      *(float4*)(ctx_g + bg * 128 + l16 * 8 + 4) = n1;
    }
  }
  __syncthreads();
  for (int bb = 0; bb < 16; ++bb) {
    const int bg = bT + bb;
    const int ch = chars_[bg];
    for (int k = tid; k < 832; k += 256) {
      float x;
      if (k < EDIM)      x = emb[ch * EDIM + k];
      else if (k < 528)  x = ctxs[bb * 128 + (k - EDIM)];
      else if (k < 828)  x = h[bg * HDIM + (k - 528)];
      else               x = 0.f;
      Xs[bb * 836 + k] = x;
    }
  }
  __syncthreads();
  const int bLoc = tid & 15;
  const int jLoc = tid >> 4;
  const int j0 = jT + jLoc * 2;
  if (j0 >= GDIM) return;
  const int j1 = j0 + 1;
  const int bg = bT + bLoc;
  float acc0 = 0.f, acc1 = 0.f;
  const float4* xr = (const float4*)(Xs + bLoc * 836);
  {
    const float4* w0 = (const float4*)(W_ih + (size_t)j0 * 528);
    const float4* w1 = (const float4*)(W_ih + (size_t)j1 * 528);
#pragma unroll 4
    for (int k4 = 0; k4 < 132; ++k4) {
      const float4 xv = xr[k4];
      const float4 a = w0[k4];
      const float4 bv = w1[k4];
      acc0 += xv.x * a.x + xv.y * a.y + xv.z * a.z + xv.w * a.w;
      acc1 += xv.x * bv.x + xv.y * bv.y + xv.z * bv.z + xv.w * bv.w;
    }
  }
  {
    const float4* xh = (const float4*)(Xs + bLoc * 836 + 528);
    const float4* g0 = (const float4*)(W_hh + (size_t)j0 * HDIM);
    const float4* g1 = (const float4*)(W_hh + (size_t)j1 * HDIM);
#pragma unroll 4
    for (int k4 = 0; k4 < 75; ++k4) {
      const float4 xv = xh[k4];
      const float4 a = g0[k4];
      const float4 bv = g1[k4];
      acc0 += xv.x * a.x + xv.y * a.y + xv.z * a.z + xv.w * a.w;
      acc1 += xv.x * bv.x + xv.y * bv.y + xv.z * bv.z + xv.w * bv.w;
    }
  }
  gates[bg * GDIM + j0] = acc0 + b_ih[j0] + b_hh[j0];
  gates[bg * GDIM + j1] = acc1 + b_ih[j1] + b_hh[j1];
}

// ---------------------------------------------------------------------------
// Legacy fused k_att (fallback when workspace can't hold fp16 copies).
__global__ __launch_bounds__(256) void k_att_fb(
    const float* __restrict__ keys, const float* __restrict__ values,
    const float* __restrict__ gates, const float* __restrict__ ctx_g,
    const float* __restrict__ W_proj, const float* __restrict__ b_proj,
    const float* __restrict__ b_phi, const float* __restrict__ wphiT,
    const float* __restrict__ c_in, float* __restrict__ c_out,
    float* __restrict__ h, const float* __restrict__ query_g,
    int* __restrict__ chars_, float* __restrict__ partials,
    float* __restrict__ out, int step) {
  const int b = blockIdx.x, chunk = blockIdx.y, tid = threadIdx.x;
  __shared__ float hs_cat[HDIM + VDIM];
  __shared__ float logit_s[NVOCAB];
  __shared__ float qs[KDIM];
  __shared__ float e_s[CHT];
  __shared__ float att[CHT];
  __shared__ float red[8];
  __shared__ __align__(16) float redv[8 * 33 * 4];

  if (step >= 0) {
    for (int j = tid; j < HDIM; j += 256) {
      const float gi = gates[b * GDIM + j];
      const float gf = gates[b * GDIM + HDIM + j];
      const float gg = gates[b * GDIM + 2 * HDIM + j];
      const float go = gates[b * GDIM + 3 * HDIM + j];
      const float cc = c_in[b * HDIM + j];
      const float si = 1.f / (1.f + expf(-gi));
      const float sf = 1.f / (1.f + expf(-gf));
      const float so = 1.f / (1.f + expf(-go));
      const float cn = sf * cc + si * tanhf(gg);
      const float hn = so * tanhf(cn);
      hs_cat[j] = hn;
      if (chunk == 0) { c_out[b * HDIM + j] = cn; h[b * HDIM + j] = hn; }
    }
    if (chunk == 0 && tid < VDIM) hs_cat[HDIM + tid] = ctx_g[b * VDIM + tid];
    __syncthreads();
    if (chunk == 0) {
      const int w = tid >> 6, l = tid & 63;
      for (int j = w; j < NVOCAB; j += 4) {
        float p = 0.f;
        for (int e = l; e < HDIM + VDIM; e += 64) p += hs_cat[e] * W_proj[j * 428 + e];
        p += __shfl_xor(p, 1); p += __shfl_xor(p, 2); p += __shfl_xor(p, 4);
        p += __shfl_xor(p, 8); p += __shfl_xor(p, 16); p += __shfl_xor(p, 32);
        if (l == 0) logit_s[j] = p + b_proj[j];
      }
      __syncthreads();
      if (tid < NVOCAB) out[((size_t)step * BATCH + b) * NVOCAB + tid] = logit_s[tid];
      if (tid == 0) {
        float best = logit_s[0];
        int bi = 0;
        for (int j = 1; j < NVOCAB; ++j)
          if (logit_s[j] > best) { best = logit_s[j]; bi = j; }
        chars_[b] = bi;
        out[NLOGITS + (size_t)step * BATCH + b] = (float)bi;
      }
    }
    if (tid < KDIM) {
      float q = b_phi[tid];
      for (int j = 0; j < HDIM; ++j) q += hs_cat[j] * wphiT[j * KDIM + tid];
      qs[tid] = q;
    }
  } else {
    if (tid < KDIM) qs[tid] = query_g[b * KDIM + tid];
  }
  __syncthreads();

  const int wave = tid >> 6, lane = tid & 63;
  const int half = lane >> 5, l32 = lane & 31;
  {
    const float4 q4 = *(const float4*)(qs + l32 * 4);
    const int tl0 = wave * 32;
    for (int i = 0; i < 16; ++i) {
      const int tl = tl0 + 2 * i + half;
      const int t = chunk * CHT + tl;
      const float4 kv = *(const float4*)(keys + ((size_t)t * BATCH + b) * KDIM + l32 * 4);
      float p = q4.x * kv.x + q4.y * kv.y + q4.z * kv.z + q4.w * kv.w;
      p += __shfl_xor(p, 1); p += __shfl_xor(p, 2); p += __shfl_xor(p, 4);
      p += __shfl_xor(p, 8); p += __shfl_xor(p, 16);
      if (l32 == 0) e_s[tl] = p;
    }
  }
  __syncthreads();

  float m = (tid < CHT) ? e_s[tid] : -INFINITY;
  for (int off = 32; off; off >>= 1) m = fmaxf(m, __shfl_xor(m, off));
  if ((tid & 63) == 0) red[tid >> 6] = m;
  __syncthreads();
  const float M = fmaxf(fmaxf(red[0], red[1]), fmaxf(red[2], red[3]));
  float ex = 0.f;
  if (tid < CHT) { ex = expf(e_s[tid] - M); att[tid] = ex; }
  for (int off = 32; off; off >>= 1) ex += __shfl_xor(ex, off);
  if ((tid & 63) == 0) red[4 + (tid >> 6)] = ex;
  __syncthreads();
  const float S = red[4] + red[5] + red[6] + red[7];

  const int v4 = tid & 31, tsub = tid >> 5;
  float4 acc = make_float4(0.f, 0.f, 0.f, 0.f);
  const float* vb = values + (size_t)b * VDIM + v4 * 4;
  for (int i = 0; i < 16; ++i) {
    const int tl = i * 8 + tsub;
    const float a = att[tl];
    const float4 val = *(const float4*)(vb + (size_t)(chunk * CHT + tl) * BATCH * VDIM);
    acc.x += a * val.x; acc.y += a * val.y; acc.z += a * val.z; acc.w += a * val.w;
  }
  *(float4*)(redv + (tsub * 33 + v4) * 4) = acc;
  __syncthreads();
  const size_t r = (size_t)b * NCHUNK + chunk;
  if (tid < 32) {
    float4 s4 = *(const float4*)(redv + tid * 4);
    for (int p = 1; p < 8; ++p) {
      const float4 rr = *(const float4*)(redv + (p * 33 + tid) * 4);
      s4.x += rr.x; s4.y += rr.y; s4.z += rr.z; s4.w += rr.w;
    }
    *(float4*)(partials + r * PROW + tid * 4) = s4;
  }
  if (tid == 0) {
    partials[r * PROW + 128] = M;
    partials[r * PROW + 129] = S;
  }
}

// ---------------------------------------------------------------------------
extern "C" void kernel_launch(void* const* d_in, const int* in_sizes, int n_in,
                              void* d_out, int out_size, void* d_ws, size_t ws_size,
                              hipStream_t stream) {
  (void)in_sizes; (void)n_in; (void)out_size;
  const float* keys   = (const float*)d_in[0];
  const float* values = (const float*)d_in[1];
  const float* emb    = (const float*)d_in[2];
  const float* W_phi  = (const float*)d_in[3];
  const float* b_phi  = (const float*)d_in[4];
  const float* W_ih   = (const float*)d_in[5];
  const float* b_ih   = (const float*)d_in[6];
  const float* W_hh   = (const float*)d_in[7];
  const float* b_hh   = (const float*)d_in[8];
  const float* W_proj = (const float*)d_in[9];
  const float* b_proj = (const float*)d_in[10];
  const float* h0     = (const float*)d_in[11];
  const float* c0     = (const float*)d_in[12];
  float* out = (float*)d_out;

  float* F = (float*)d_ws;
  float* f_h     = F + OFF_H;
  float* f_c[2]  = {F + OFF_C0, F + OFF_C1};
  float* f_gates = F + OFF_GATES;
  float* f_query = F + OFF_QUERY;
  float* f_ctx   = F + OFF_CTX;
  float* f_wphiT = F + OFF_WPHIT;
  float* f_part  = F + OFF_PART;
  int*   i_chars = (int*)(F + OFF_CHARS);

  k_transpose<<<150, 256, 0, stream>>>(W_phi, f_wphiT);
  k_init<<<BATCH, 128, 0, stream>>>(h0, c0, b_phi, f_wphiT, f_h, f_c[0],
                                    f_query, i_chars);

  const bool big = ws_size >= WS_NEED_F * sizeof(float);
  if (big) {
    __half* kH = (__half*)(F + OFF_KVH);
    __half* vH = kH + NKV;
    k_tohalf<<<dim3(BATCH, SEQ_T / 16), 256, 0, stream>>>(keys, kH);
    k_tohalf<<<dim3(BATCH, SEQ_T / 16), 256, 0, stream>>>(values, vH);
    // initial attend(h0): query from k_init
    k_att3<<<dim3(BATCH, NCHUNK), 256, 0, stream>>>(
        kH, vH, f_gates, f_ctx, W_proj, b_proj, b_phi, f_wphiT,
        f_c[0], f_c[1], f_h, f_query, i_chars, f_part, out, -1);
    for (int s = 0; s < MAXLEN; ++s) {
      k_gates<<<dim3(8, 38), 256, 0, stream>>>(
          emb, i_chars, f_part, f_h, W_ih, b_ih, W_hh, b_hh, f_gates, f_ctx);
      k_att3<<<dim3(BATCH, NCHUNK), 256, 0, stream>>>(
          kH, vH, f_gates, f_ctx, W_proj, b_proj, b_phi, f_wphiT,
          f_c[s & 1], f_c[(s + 1) & 1], f_h, f_query, i_chars, f_part, out, s);
    }
  } else {
    // legacy path (proven): fused cell+att streaming over f32 [T][B][K]
    k_att_fb<<<dim3(BATCH, NCHUNK), 256, 0, stream>>>(
        keys, values, f_gates, f_ctx, W_proj, b_proj, b_phi, f_wphiT,
        f_c[0], f_c[1], f_h, f_query, i_chars, f_part, out, -1);
    for (int s = 0; s < MAXLEN; ++s) {
      k_gates<<<dim3(8, 38), 256, 0, stream>>>(
          emb, i_chars, f_part, f_h, W_ih, b_ih, W_hh, b_hh, f_gates, f_ctx);
      k_att_fb<<<dim3(BATCH, NCHUNK), 256, 0, stream>>>(
          keys, values, f_gates, f_ctx, W_proj, b_proj, b_phi, f_wphiT,
          f_c[s & 1], f_c[(s + 1) & 1], f_h, f_query, i_chars, f_part, out, s);
    }
  }
}

// Round 4
// 40990.002 us; speedup vs baseline: 1.3831x; 1.1999x over previous
//
#include <hip/hip_runtime.h>
#include <hip/hip_fp16.h>
#include <math.h>

// ---- problem constants ----
constexpr int SEQ_T  = 2048;
constexpr int BATCH  = 128;
constexpr int KDIM   = 128;
constexpr int VDIM   = 128;
constexpr int EDIM   = 400;
constexpr int HDIM   = 300;
constexpr int GDIM   = 1200;    // 4*H
constexpr int NVOCAB = 33;
constexpr int MAXLEN = 500;
constexpr int SOS_TOK = 5;
constexpr int NCHUNK = 16;      // t-chunks per b
constexpr int CHT    = 128;     // t per chunk
constexpr int PROW   = 136;     // floats per partial row: accV[128], M, S, pad
constexpr long long NLOGITS = (long long)MAXLEN * BATCH * NVOCAB; // 2,112,000

// ---- ws float-element offsets ----
constexpr size_t OFF_H     = 0;        // 128*300
constexpr size_t OFF_C0    = 38400;    // 128*300 (ping)
constexpr size_t OFF_C1    = 76800;    // 128*300 (pong)
constexpr size_t OFF_GATES = 115200;   // 128*1200
constexpr size_t OFF_QUERY = 268800;   // 128*128
constexpr size_t OFF_CTX   = 285184;   // 128*128
constexpr size_t OFF_WPHIT = 301568;   // 300*128
constexpr size_t OFF_PART  = 339968;   // 2048*136
constexpr size_t OFF_CHARS = 618496;   // 128 int
// fp16 [B][T][K] copies of keys/values (primary path). keysH occupies
// NKV halves = NKV/2 float slots; valsH right after.
constexpr size_t NKV       = (size_t)SEQ_T * BATCH * KDIM;   // 33,554,432 elems
constexpr size_t OFF_KVH   = 655360;                          // float idx
constexpr size_t WS_NEED_F = OFF_KVH + NKV;                   // ~137 MB total

// ---------------------------------------------------------------------------
// one-time: W_phi [128][300] -> W_phiT [300][128]
__global__ __launch_bounds__(256) void k_transpose(
    const float* __restrict__ W_phi, float* __restrict__ wphiT) {
  int i = blockIdx.x * 256 + threadIdx.x;
  if (i < HDIM * KDIM) {
    int j = i >> 7, kq = i & 127;
    wphiT[i] = W_phi[kq * HDIM + j];
  }
}

// one-time: h,c,chars init + initial query
__global__ __launch_bounds__(128) void k_init(
    const float* __restrict__ h0, const float* __restrict__ c0,
    const float* __restrict__ b_phi, const float* __restrict__ wphiT,
    float* __restrict__ h, float* __restrict__ c,
    float* __restrict__ query, int* __restrict__ chars_) {
  const int b = blockIdx.x;
  const int tid = threadIdx.x;
  for (int j = tid; j < HDIM; j += 128) {
    h[b * HDIM + j] = h0[j];
    c[b * HDIM + j] = c0[j];
  }
  {
    float q = b_phi[tid];
    for (int j = 0; j < HDIM; ++j) q += h0[j] * wphiT[j * KDIM + tid];
    query[b * KDIM + tid] = q;
  }
  if (tid == 0) chars_[b] = SOS_TOK;
}

// ---------------------------------------------------------------------------
// one-time: f32 [T][B][128] -> f16 [B][T][128]. RN rounding.
// grid (128 b, 128 t-tiles of 16), 256 threads.
__global__ __launch_bounds__(256) void k_tohalf(
    const float* __restrict__ src, __half* __restrict__ dst) {
  const int b  = blockIdx.x;
  const int tt = blockIdx.y * 16;
  const int tid = threadIdx.x;
  for (int i = tid; i < 512; i += 256) {      // 16 t * 32 float4
    const int tl = i >> 5, k4 = i & 31;
    const size_t t = (size_t)(tt + tl);
    const float4 v = *(const float4*)(src + (t * BATCH + b) * KDIM + k4 * 4);
    const __half2 h0 = __floats2half2_rn(v.x, v.y);
    const __half2 h1 = __floats2half2_rn(v.z, v.w);
    uint2 pk;
    pk.x = *(const unsigned int*)&h0;
    pk.y = *(const unsigned int*)&h1;
    *(uint2*)(dst + ((size_t)b * SEQ_T + t) * KDIM + k4 * 4) = pk;
  }
}

// ---------------------------------------------------------------------------
// k_att3: fused [cell -> logits/argmax (chunk0) -> query] + attention over
// fp16 [B][T][128] keys/values (proven R3; unchanged this round).
__global__ __launch_bounds__(256) void k_att3(
    const __half* __restrict__ keysH, const __half* __restrict__ valsH,
    const float* __restrict__ gates, const float* __restrict__ ctx_g,
    const float* __restrict__ W_proj, const float* __restrict__ b_proj,
    const float* __restrict__ b_phi, const float* __restrict__ wphiT,
    const float* __restrict__ c_in, float* __restrict__ c_out,
    float* __restrict__ h, const float* __restrict__ query_g,
    int* __restrict__ chars_, float* __restrict__ partials,
    float* __restrict__ out, int step) {
  const int b = blockIdx.x, chunk = blockIdx.y, tid = threadIdx.x;
  __shared__ __align__(16) float scr[2048];   // preamble: hs_cat|logits ; V: redv
  __shared__ float qs[KDIM];
  __shared__ float e_s[CHT];
  __shared__ float att[CHT];
  __shared__ float red[8];

  float* hs_cat  = scr;          // 428 (preamble only)
  float* logit_s = scr + 428;    // 33  (preamble only)
  float* redv    = scr;          // 2048 = 16 tsub x 128 dim (V phase)

  if (step >= 0) {
    // ---- LSTM cell (redundant per chunk; identical fp ops -> identical h) ----
    for (int j = tid; j < HDIM; j += 256) {
      const float gi = gates[b * GDIM + j];
      const float gf = gates[b * GDIM + HDIM + j];
      const float gg = gates[b * GDIM + 2 * HDIM + j];
      const float go = gates[b * GDIM + 3 * HDIM + j];
      const float cc = c_in[b * HDIM + j];
      const float si = 1.f / (1.f + expf(-gi));
      const float sf = 1.f / (1.f + expf(-gf));
      const float so = 1.f / (1.f + expf(-go));
      const float cn = sf * cc + si * tanhf(gg);
      const float hn = so * tanhf(cn);
      hs_cat[j] = hn;
      if (chunk == 0) { c_out[b * HDIM + j] = cn; h[b * HDIM + j] = hn; }
    }
    if (chunk == 0 && tid < VDIM) hs_cat[HDIM + tid] = ctx_g[b * VDIM + tid];
    __syncthreads();
    if (chunk == 0) {
      // ---- logits + argmax + emit (single writer: chunk0) ----
      const int w = tid >> 6, l = tid & 63;
      for (int j = w; j < NVOCAB; j += 4) {
        float p = 0.f;
        for (int e = l; e < HDIM + VDIM; e += 64) p += hs_cat[e] * W_proj[j * 428 + e];
        p += __shfl_xor(p, 1); p += __shfl_xor(p, 2); p += __shfl_xor(p, 4);
        p += __shfl_xor(p, 8); p += __shfl_xor(p, 16); p += __shfl_xor(p, 32);
        if (l == 0) logit_s[j] = p + b_proj[j];
      }
      __syncthreads();
      if (tid < NVOCAB) out[((size_t)step * BATCH + b) * NVOCAB + tid] = logit_s[tid];
      if (tid == 0) {
        float best = logit_s[0];
        int bi = 0;
        for (int j = 1; j < NVOCAB; ++j)
          if (logit_s[j] > best) { best = logit_s[j]; bi = j; }  // np first-max
        chars_[b] = bi;
        out[NLOGITS + (size_t)step * BATCH + b] = (float)bi;
      }
    }
    // ---- query from h_new ----
    if (tid < KDIM) {
      float q0 = b_phi[tid], q1 = 0.f;
      for (int j = 0; j < HDIM; j += 2) {
        q0 += hs_cat[j]     * wphiT[j * KDIM + tid];
        q1 += hs_cat[j + 1] * wphiT[(j + 1) * KDIM + tid];
      }
      qs[tid] = q0 + q1;
    }
  } else {
    if (tid < KDIM) qs[tid] = query_g[b * KDIM + tid];
  }
  __syncthreads();

  // ---- energy over this chunk's 128 t (fp16 K, f32 math) ----
  {
    const int wv = tid >> 6, ln = tid & 63;
    const int tq = ln >> 4, l16 = ln & 15;
    float qf[8];
#pragma unroll
    for (int j = 0; j < 8; ++j) qf[j] = qs[l16 * 8 + j];
    const __half* kb = keysH + ((size_t)b * SEQ_T + (size_t)chunk * CHT) * KDIM;
#pragma unroll
    for (int r = 0; r < 8; ++r) {
      const int tl = r * 16 + wv * 4 + tq;
      const uint4 raw = *(const uint4*)(kb + (size_t)tl * KDIM + l16 * 8);
      union { uint4 u; __half2 h[4]; } c; c.u = raw;
      const float2 f0 = __half22float2(c.h[0]);
      const float2 f1 = __half22float2(c.h[1]);
      const float2 f2 = __half22float2(c.h[2]);
      const float2 f3 = __half22float2(c.h[3]);
      float p = qf[0] * f0.x + qf[1] * f0.y + qf[2] * f1.x + qf[3] * f1.y
              + qf[4] * f2.x + qf[5] * f2.y + qf[6] * f3.x + qf[7] * f3.y;
      p += __shfl_xor(p, 1); p += __shfl_xor(p, 2);
      p += __shfl_xor(p, 4); p += __shfl_xor(p, 8);
      if (l16 == 0) e_s[tl] = p;
    }
  }
  __syncthreads();

  // ---- chunk-local softmax stats (M_c, S_c) — verbatim baseline ----
  float m = (tid < CHT) ? e_s[tid] : -INFINITY;
  for (int off = 32; off; off >>= 1) m = fmaxf(m, __shfl_xor(m, off));
  if ((tid & 63) == 0) red[tid >> 6] = m;
  __syncthreads();
  const float M = fmaxf(fmaxf(red[0], red[1]), fmaxf(red[2], red[3]));
  float ex = 0.f;
  if (tid < CHT) { ex = expf(e_s[tid] - M); att[tid] = ex; }
  for (int off = 32; off; off >>= 1) ex += __shfl_xor(ex, off);
  if ((tid & 63) == 0) red[4 + (tid >> 6)] = ex;
  __syncthreads();
  const float S = red[4] + red[5] + red[6] + red[7];

  // ---- unnormalized weighted V accumulation (fp16 V, f32 accumulate) ----
  {
    const int d16 = tid & 15, tsub = tid >> 4;   // 16 dim-groups x 16 t-lanes
    const __half* vb = valsH + ((size_t)b * SEQ_T + (size_t)chunk * CHT) * KDIM;
    float av[8] = {0.f, 0.f, 0.f, 0.f, 0.f, 0.f, 0.f, 0.f};
#pragma unroll
    for (int r = 0; r < 8; ++r) {
      const int tl = r * 16 + tsub;
      const float a = att[tl];
      const uint4 raw = *(const uint4*)(vb + (size_t)tl * KDIM + d16 * 8);
      union { uint4 u; __half2 h[4]; } c; c.u = raw;
      const float2 f0 = __half22float2(c.h[0]);
      const float2 f1 = __half22float2(c.h[1]);
      const float2 f2 = __half22float2(c.h[2]);
      const float2 f3 = __half22float2(c.h[3]);
      av[0] += a * f0.x; av[1] += a * f0.y; av[2] += a * f1.x; av[3] += a * f1.y;
      av[4] += a * f2.x; av[5] += a * f2.y; av[6] += a * f3.x; av[7] += a * f3.y;
    }
    __syncthreads();   // preamble/scr reuse & att reads done
    *(float4*)(redv + tsub * 128 + d16 * 8)     = make_float4(av[0], av[1], av[2], av[3]);
    *(float4*)(redv + tsub * 128 + d16 * 8 + 4) = make_float4(av[4], av[5], av[6], av[7]);
  }
  __syncthreads();
  const size_t rrow = (size_t)b * NCHUNK + chunk;
  if (tid < 128) {
    float sacc = 0.f;
#pragma unroll
    for (int p = 0; p < 16; ++p) sacc += redv[p * 128 + tid];  // fixed order
    partials[rrow * PROW + tid] = sacc;
  }
  if (tid == 0) {
    partials[rrow * PROW + 128] = M;
    partials[rrow * PROW + 129] = S;
  }
}

// ---------------------------------------------------------------------------
// k_gates: [combine partials -> ctx] + gates GEMM.
// THIS ROUND: latency-bound fix. Old geometry: grid (8,38)=304 blocks
// (1.19 blocks/CU, ~1.2 waves/SIMD) with 621 float4 L2 loads per thread ->
// load-latency exposed. New: grid (16 bT, 75 jT)=1200 blocks x 128 threads,
// 1 output per thread (8 b x 16 j per block), __launch_bounds__(128,4)
// (8 blocks/CU target), unroll 8. Per-output k-accumulation order is
// UNCHANGED -> bit-identical gates. Combine/staging math unchanged.
__global__ __launch_bounds__(128, 4) void k_gates(
    const float* __restrict__ emb, const int* __restrict__ chars_,
    const float* __restrict__ partials, const float* __restrict__ h,
    const float* __restrict__ W_ih, const float* __restrict__ b_ih,
    const float* __restrict__ W_hh, const float* __restrict__ b_hh,
    float* __restrict__ gates, float* __restrict__ ctx_g) {
  const int bT = blockIdx.x * 8;      // 8 b per block
  const int jT = blockIdx.y * 16;     // 16 j per block
  const int tid = threadIdx.x;
  __shared__ float Xs[8 * 836];
  __shared__ float ctxs[8 * 128];
  // ---- combine: ctx[b] from 16 chunk partials (verbatim math, 8 b) ----
  {
    const int bl = tid >> 4, l16 = tid & 15;    // 8 b x 16 lanes (8 dims each)
    const int bg = bT + bl;
    const float* pb = partials + (size_t)bg * NCHUNK * PROW;
    float M = -INFINITY;
    for (int ci = 0; ci < NCHUNK; ++ci) M = fmaxf(M, pb[ci * PROW + 128]);
    float den = 0.f;
    float4 n0 = make_float4(0.f, 0.f, 0.f, 0.f);
    float4 n1 = make_float4(0.f, 0.f, 0.f, 0.f);
    for (int ci = 0; ci < NCHUNK; ++ci) {
      const float w = expf(pb[ci * PROW + 128] - M);
      den += w * pb[ci * PROW + 129];
      const float4 a0 = *(const float4*)(pb + ci * PROW + l16 * 8);
      const float4 a1 = *(const float4*)(pb + ci * PROW + l16 * 8 + 4);
      n0.x += w * a0.x; n0.y += w * a0.y; n0.z += w * a0.z; n0.w += w * a0.w;
      n1.x += w * a1.x; n1.y += w * a1.y; n1.z += w * a1.z; n1.w += w * a1.w;
    }
    const float inv = 1.f / den;
    n0.x *= inv; n0.y *= inv; n0.z *= inv; n0.w *= inv;
    n1.x *= inv; n1.y *= inv; n1.z *= inv; n1.w *= inv;
    *(float4*)(ctxs + bl * 128 + l16 * 8)     = n0;
    *(float4*)(ctxs + bl * 128 + l16 * 8 + 4) = n1;
    if (blockIdx.y == 0) {
      *(float4*)(ctx_g + bg * 128 + l16 * 8)     = n0;
      *(float4*)(ctx_g + bg * 128 + l16 * 8 + 4) = n1;
    }
  }
  __syncthreads();
  // ---- stage x = [emb | ctx | h] (identical element values) ----
  for (int bb = 0; bb < 8; ++bb) {
    const int bg = bT + bb;
    const int ch = chars_[bg];
    for (int k = tid; k < 832; k += 128) {
      float x;
      if (k < EDIM)      x = emb[ch * EDIM + k];
      else if (k < 528)  x = ctxs[bb * 128 + (k - EDIM)];
      else if (k < 828)  x = h[bg * HDIM + (k - 528)];
      else               x = 0.f;
      Xs[bb * 836 + k] = x;
    }
  }
  __syncthreads();
  // ---- gates GEMM: 1 output per thread, same k-order as proven kernel ----
  const int bLoc = tid & 7;           // 8 b
  const int jLoc = tid >> 3;          // 16 j
  const int j = jT + jLoc;
  const int bg = bT + bLoc;
  float acc = 0.f;
  const float4* xr = (const float4*)(Xs + bLoc * 836);
  {
    const float4* w0 = (const float4*)(W_ih + (size_t)j * 528);
#pragma unroll 8
    for (int k4 = 0; k4 < 132; ++k4) {
      const float4 xv = xr[k4];
      const float4 a = w0[k4];
      acc += xv.x * a.x + xv.y * a.y + xv.z * a.z + xv.w * a.w;
    }
  }
  {
    const float4* xh = (const float4*)(Xs + bLoc * 836 + 528);
    const float4* g0 = (const float4*)(W_hh + (size_t)j * HDIM);
#pragma unroll 8
    for (int k4 = 0; k4 < 75; ++k4) {
      const float4 xv = xh[k4];
      const float4 a = g0[k4];
      acc += xv.x * a.x + xv.y * a.y + xv.z * a.z + xv.w * a.w;
    }
  }
  gates[bg * GDIM + j] = acc + b_ih[j] + b_hh[j];
}

// ---------------------------------------------------------------------------
// Legacy fused k_att (fallback when workspace can't hold fp16 copies).
__global__ __launch_bounds__(256) void k_att_fb(
    const float* __restrict__ keys, const float* __restrict__ values,
    const float* __restrict__ gates, const float* __restrict__ ctx_g,
    const float* __restrict__ W_proj, const float* __restrict__ b_proj,
    const float* __restrict__ b_phi, const float* __restrict__ wphiT,
    const float* __restrict__ c_in, float* __restrict__ c_out,
    float* __restrict__ h, const float* __restrict__ query_g,
    int* __restrict__ chars_, float* __restrict__ partials,
    float* __restrict__ out, int step) {
  const int b = blockIdx.x, chunk = blockIdx.y, tid = threadIdx.x;
  __shared__ float hs_cat[HDIM + VDIM];
  __shared__ float logit_s[NVOCAB];
  __shared__ float qs[KDIM];
  __shared__ float e_s[CHT];
  __shared__ float att[CHT];
  __shared__ float red[8];
  __shared__ __align__(16) float redv[8 * 33 * 4];

  if (step >= 0) {
    for (int j = tid; j < HDIM; j += 256) {
      const float gi = gates[b * GDIM + j];
      const float gf = gates[b * GDIM + HDIM + j];
      const float gg = gates[b * GDIM + 2 * HDIM + j];
      const float go = gates[b * GDIM + 3 * HDIM + j];
      const float cc = c_in[b * HDIM + j];
      const float si = 1.f / (1.f + expf(-gi));
      const float sf = 1.f / (1.f + expf(-gf));
      const float so = 1.f / (1.f + expf(-go));
      const float cn = sf * cc + si * tanhf(gg);
      const float hn = so * tanhf(cn);
      hs_cat[j] = hn;
      if (chunk == 0) { c_out[b * HDIM + j] = cn; h[b * HDIM + j] = hn; }
    }
    if (chunk == 0 && tid < VDIM) hs_cat[HDIM + tid] = ctx_g[b * VDIM + tid];
    __syncthreads();
    if (chunk == 0) {
      const int w = tid >> 6, l = tid & 63;
      for (int j = w; j < NVOCAB; j += 4) {
        float p = 0.f;
        for (int e = l; e < HDIM + VDIM; e += 64) p += hs_cat[e] * W_proj[j * 428 + e];
        p += __shfl_xor(p, 1); p += __shfl_xor(p, 2); p += __shfl_xor(p, 4);
        p += __shfl_xor(p, 8); p += __shfl_xor(p, 16); p += __shfl_xor(p, 32);
        if (l == 0) logit_s[j] = p + b_proj[j];
      }
      __syncthreads();
      if (tid < NVOCAB) out[((size_t)step * BATCH + b) * NVOCAB + tid] = logit_s[tid];
      if (tid == 0) {
        float best = logit_s[0];
        int bi = 0;
        for (int j = 1; j < NVOCAB; ++j)
          if (logit_s[j] > best) { best = logit_s[j]; bi = j; }
        chars_[b] = bi;
        out[NLOGITS + (size_t)step * BATCH + b] = (float)bi;
      }
    }
    if (tid < KDIM) {
      float q = b_phi[tid];
      for (int j = 0; j < HDIM; ++j) q += hs_cat[j] * wphiT[j * KDIM + tid];
      qs[tid] = q;
    }
  } else {
    if (tid < KDIM) qs[tid] = query_g[b * KDIM + tid];
  }
  __syncthreads();

  const int wave = tid >> 6, lane = tid & 63;
  const int half = lane >> 5, l32 = lane & 31;
  {
    const float4 q4 = *(const float4*)(qs + l32 * 4);
    const int tl0 = wave * 32;
    for (int i = 0; i < 16; ++i) {
      const int tl = tl0 + 2 * i + half;
      const int t = chunk * CHT + tl;
      const float4 kv = *(const float4*)(keys + ((size_t)t * BATCH + b) * KDIM + l32 * 4);
      float p = q4.x * kv.x + q4.y * kv.y + q4.z * kv.z + q4.w * kv.w;
      p += __shfl_xor(p, 1); p += __shfl_xor(p, 2); p += __shfl_xor(p, 4);
      p += __shfl_xor(p, 8); p += __shfl_xor(p, 16);
      if (l32 == 0) e_s[tl] = p;
    }
  }
  __syncthreads();

  float m = (tid < CHT) ? e_s[tid] : -INFINITY;
  for (int off = 32; off; off >>= 1) m = fmaxf(m, __shfl_xor(m, off));
  if ((tid & 63) == 0) red[tid >> 6] = m;
  __syncthreads();
  const float M = fmaxf(fmaxf(red[0], red[1]), fmaxf(red[2], red[3]));
  float ex = 0.f;
  if (tid < CHT) { ex = expf(e_s[tid] - M); att[tid] = ex; }
  for (int off = 32; off; off >>= 1) ex += __shfl_xor(ex, off);
  if ((tid & 63) == 0) red[4 + (tid >> 6)] = ex;
  __syncthreads();
  const float S = red[4] + red[5] + red[6] + red[7];

  const int v4 = tid & 31, tsub = tid >> 5;
  float4 acc = make_float4(0.f, 0.f, 0.f, 0.f);
  const float* vb = values + (size_t)b * VDIM + v4 * 4;
  for (int i = 0; i < 16; ++i) {
    const int tl = i * 8 + tsub;
    const float a = att[tl];
    const float4 val = *(const float4*)(vb + (size_t)(chunk * CHT + tl) * BATCH * VDIM);
    acc.x += a * val.x; acc.y += a * val.y; acc.z += a * val.z; acc.w += a * val.w;
  }
  *(float4*)(redv + (tsub * 33 + v4) * 4) = acc;
  __syncthreads();
  const size_t r = (size_t)b * NCHUNK + chunk;
  if (tid < 32) {
    float4 s4 = *(const float4*)(redv + tid * 4);
    for (int p = 1; p < 8; ++p) {
      const float4 rr = *(const float4*)(redv + (p * 33 + tid) * 4);
      s4.x += rr.x; s4.y += rr.y; s4.z += rr.z; s4.w += rr.w;
    }
    *(float4*)(partials + r * PROW + tid * 4) = s4;
  }
  if (tid == 0) {
    partials[r * PROW + 128] = M;
    partials[r * PROW + 129] = S;
  }
}

// ---------------------------------------------------------------------------
extern "C" void kernel_launch(void* const* d_in, const int* in_sizes, int n_in,
                              void* d_out, int out_size, void* d_ws, size_t ws_size,
                              hipStream_t stream) {
  (void)in_sizes; (void)n_in; (void)out_size;
  const float* keys   = (const float*)d_in[0];
  const float* values = (const float*)d_in[1];
  const float* emb    = (const float*)d_in[2];
  const float* W_phi  = (const float*)d_in[3];
  const float* b_phi  = (const float*)d_in[4];
  const float* W_ih   = (const float*)d_in[5];
  const float* b_ih   = (const float*)d_in[6];
  const float* W_hh   = (const float*)d_in[7];
  const float* b_hh   = (const float*)d_in[8];
  const float* W_proj = (const float*)d_in[9];
  const float* b_proj = (const float*)d_in[10];
  const float* h0     = (const float*)d_in[11];
  const float* c0     = (const float*)d_in[12];
  float* out = (float*)d_out;

  float* F = (float*)d_ws;
  float* f_h     = F + OFF_H;
  float* f_c[2]  = {F + OFF_C0, F + OFF_C1};
  float* f_gates = F + OFF_GATES;
  float* f_query = F + OFF_QUERY;
  float* f_ctx   = F + OFF_CTX;
  float* f_wphiT = F + OFF_WPHIT;
  float* f_part  = F + OFF_PART;
  int*   i_chars = (int*)(F + OFF_CHARS);

  k_transpose<<<150, 256, 0, stream>>>(W_phi, f_wphiT);
  k_init<<<BATCH, 128, 0, stream>>>(h0, c0, b_phi, f_wphiT, f_h, f_c[0],
                                    f_query, i_chars);

  const bool big = ws_size >= WS_NEED_F * sizeof(float);
  if (big) {
    __half* kH = (__half*)(F + OFF_KVH);
    __half* vH = kH + NKV;
    k_tohalf<<<dim3(BATCH, SEQ_T / 16), 256, 0, stream>>>(keys, kH);
    k_tohalf<<<dim3(BATCH, SEQ_T / 16), 256, 0, stream>>>(values, vH);
    // initial attend(h0): query from k_init
    k_att3<<<dim3(BATCH, NCHUNK), 256, 0, stream>>>(
        kH, vH, f_gates, f_ctx, W_proj, b_proj, b_phi, f_wphiT,
        f_c[0], f_c[1], f_h, f_query, i_chars, f_part, out, -1);
    for (int s = 0; s < MAXLEN; ++s) {
      k_gates<<<dim3(16, 75), 128, 0, stream>>>(
          emb, i_chars, f_part, f_h, W_ih, b_ih, W_hh, b_hh, f_gates, f_ctx);
      k_att3<<<dim3(BATCH, NCHUNK), 256, 0, stream>>>(
          kH, vH, f_gates, f_ctx, W_proj, b_proj, b_phi, f_wphiT,
          f_c[s & 1], f_c[(s + 1) & 1], f_h, f_query, i_chars, f_part, out, s);
    }
  } else {
    // legacy path (proven): fused cell+att streaming over f32 [T][B][K]
    k_att_fb<<<dim3(BATCH, NCHUNK), 256, 0, stream>>>(
        keys, values, f_gates, f_ctx, W_proj, b_proj, b_phi, f_wphiT,
        f_c[0], f_c[1], f_h, f_query, i_chars, f_part, out, -1);
    for (int s = 0; s < MAXLEN; ++s) {
      k_gates<<<dim3(16, 75), 128, 0, stream>>>(
          emb, i_chars, f_part, f_h, W_ih, b_ih, W_hh, b_hh, f_gates, f_ctx);
      k_att_fb<<<dim3(BATCH, NCHUNK), 256, 0, stream>>>(
          keys, values, f_gates, f_ctx, W_proj, b_proj, b_phi, f_wphiT,
          f_c[s & 1], f_c[(s + 1) & 1], f_h, f_query, i_chars, f_part, out, s);
    }
  }
}